// Round 1
// baseline (1542.722 us; speedup 1.0000x reference)
//
#include <hip/hip_runtime.h>
#include <cmath>

#define B_ 4
#define N_ 4096
#define NF_ 8192
#define K_ 512
#define C_ 128
#define L_ 4
#define FCD_ 128

// ---- workspace layout (float offsets) ----
static const size_t COSV_OFF = 0;                               // B*K*N
static const size_t SINV_OFF = COSV_OFF + (size_t)B_*K_*N_;     // B*K*N
static const size_t H_OFF    = SINV_OFF + (size_t)B_*K_*N_;     // B*C*N
static const size_t H2_OFF   = H_OFF    + (size_t)B_*C_*N_;     // B*C*N
static const size_t WQN_OFF  = H2_OFF   + (size_t)B_*C_*N_;     // B*N
static const size_t XCH_OFF  = WQN_OFF  + (size_t)B_*N_;        // B*C*K
static const size_t XSH_OFF  = XCH_OFF  + (size_t)B_*C_*K_;
static const size_t FCH_OFF  = XSH_OFF  + (size_t)B_*C_*K_;
static const size_t FSH_OFF  = FCH_OFF  + (size_t)B_*C_*K_;
static const size_t X0_OFF   = FSH_OFF  + (size_t)B_*C_*K_;     // B*C
static const size_t F0_OFF   = X0_OFF   + (size_t)B_*C_;        // B*C
static const size_t XCP_OFF  = F0_OFF   + (size_t)B_*C_;        // 4*B*C*K
static const size_t XSP_OFF  = XCP_OFF  + (size_t)4*B_*C_*K_;   // 4*B*C*K

__device__ __forceinline__ float gelu_exact(float v) {
    return v * 0.5f * (1.0f + erff(v * 0.70710678118654752440f));
}

// h[b,c,n] = fc0(x);  wqn[b,n] = wq[b,ind[n]] * N
__global__ void prep_kernel(const float* __restrict__ x, const float* __restrict__ xf,
                            const int* __restrict__ ind, const float* __restrict__ fc0_w,
                            const float* __restrict__ fc0_b, float* __restrict__ h,
                            float* __restrict__ wqn) {
    int n = blockIdx.x * 256 + threadIdx.x;
    int c = blockIdx.y;
    int b = blockIdx.z;
    const float* xp = x + ((size_t)b * N_ + n) * 3;
    float acc = fc0_b[c] + xp[0] * fc0_w[0 * C_ + c] + xp[1] * fc0_w[1 * C_ + c]
              + xp[2] * fc0_w[2 * C_ + c];
    h[((size_t)b * C_ + c) * N_ + n] = acc;
    if (c == 0) {
        int g = ind[n];
        wqn[b * N_ + n] = xf[((size_t)b * NF_ + g) * 4 + 2] * (float)N_;
    }
}

// cosv/sinv[b,k,n] at gathered grid points
__global__ void bases_kernel(const float* __restrict__ xf, const int* __restrict__ ind,
                             const float* __restrict__ modes, float* __restrict__ cosv,
                             float* __restrict__ sinv) {
    int n = blockIdx.x * 256 + threadIdx.x;
    int k = blockIdx.y;
    int b = blockIdx.z;
    int g = ind[n];
    float gx = xf[((size_t)b * NF_ + g) * 4 + 0];
    float gy = xf[((size_t)b * NF_ + g) * 4 + 1];
    float t = gx * modes[k * 2 + 0] + gy * modes[k * 2 + 1];
    float s, c;
    sincosf(t, &s, &c);
    size_t o = ((size_t)b * K_ + k) * N_ + n;
    cosv[o] = c;
    sinv[o] = s;
}

// xch_part[p,b,c,k] = sum_{n in chunk p} h*wqn*cos ; xsh_part = -sum h*wqn*sin
__global__ __launch_bounds__(256) void fwd_gemm(const float* __restrict__ h,
        const float* __restrict__ wqn, const float* __restrict__ cosv,
        const float* __restrict__ sinv, float* __restrict__ xcp, float* __restrict__ xsp) {
    __shared__ __align__(16) float hA[64 * 36];
    __shared__ __align__(16) float cB[64 * 36];
    __shared__ __align__(16) float sB[64 * 36];
    int tid = threadIdx.x;
    int k0 = blockIdx.x * 64, c0 = blockIdx.y * 64;
    int b = blockIdx.z >> 2, p = blockIdx.z & 3;
    int tx = tid & 15, ty = tid >> 4;
    int srow = tid >> 3, skg = tid & 7;
    float accC[4][4] = {{0}}, accS[4][4] = {{0}};
    const float* hb = h + ((size_t)b * C_ + c0) * N_;
    const float* cb = cosv + ((size_t)b * K_ + k0) * N_;
    const float* sb = sinv + ((size_t)b * K_ + k0) * N_;
    const float* wq = wqn + b * N_;
    for (int it = 0; it < 32; ++it) {
        int n0 = p * 1024 + it * 32;
        for (int pass = 0; pass < 2; ++pass) {
            int row = srow + pass * 32;
            int nn4 = skg * 4;
            float4 wv = *(const float4*)&wq[n0 + nn4];
            float4 hv = *(const float4*)&hb[(size_t)row * N_ + n0 + nn4];
            hv.x *= wv.x; hv.y *= wv.y; hv.z *= wv.z; hv.w *= wv.w;
            *(float4*)&hA[row * 36 + nn4] = hv;
            *(float4*)&cB[row * 36 + nn4] = *(const float4*)&cb[(size_t)row * N_ + n0 + nn4];
            *(float4*)&sB[row * 36 + nn4] = *(const float4*)&sb[(size_t)row * N_ + n0 + nn4];
        }
        __syncthreads();
        for (int nn = 0; nn < 32; nn += 4) {
            float4 a[4], vc[4], vs[4];
            for (int i = 0; i < 4; ++i) a[i] = *(const float4*)&hA[(ty + 16 * i) * 36 + nn];
            for (int j = 0; j < 4; ++j) {
                vc[j] = *(const float4*)&cB[(tx + 16 * j) * 36 + nn];
                vs[j] = *(const float4*)&sB[(tx + 16 * j) * 36 + nn];
            }
            for (int i = 0; i < 4; ++i)
                for (int j = 0; j < 4; ++j) {
                    accC[i][j] += a[i].x * vc[j].x + a[i].y * vc[j].y
                                + a[i].z * vc[j].z + a[i].w * vc[j].w;
                    accS[i][j] += a[i].x * vs[j].x + a[i].y * vs[j].y
                                + a[i].z * vs[j].z + a[i].w * vs[j].w;
                }
        }
        __syncthreads();
    }
    size_t pb = (size_t)p * B_ + b;
    for (int i = 0; i < 4; ++i) {
        int c = c0 + ty + 16 * i;
        for (int j = 0; j < 4; ++j) {
            int k = k0 + tx + 16 * j;
            xcp[(pb * C_ + c) * K_ + k] = accC[i][j];
            xsp[(pb * C_ + c) * K_ + k] = -accS[i][j];
        }
    }
}

__global__ void red_kernel(const float* __restrict__ xcp, const float* __restrict__ xsp,
                           float* __restrict__ xch, float* __restrict__ xsh) {
    int t = blockIdx.x * 256 + threadIdx.x;
    const int BCK = B_ * C_ * K_;
    float a = 0.f, s = 0.f;
    for (int p = 0; p < 4; ++p) { a += xcp[(size_t)p * BCK + t]; s += xsp[(size_t)p * BCK + t]; }
    xch[t] = a; xsh[t] = s;
}

// x0h[b,c] = sum_n h*wqn
__global__ void x0_kernel(const float* __restrict__ h, const float* __restrict__ wqn,
                          float* __restrict__ x0h) {
    int c = blockIdx.x, b = blockIdx.y;
    int tid = threadIdx.x;
    const float* hp = h + ((size_t)b * C_ + c) * N_;
    const float* wq = wqn + b * N_;
    float a = 0.f;
    for (int n = tid; n < N_; n += 256) a += hp[n] * wq[n];
    __shared__ float red[4];
    for (int off = 32; off; off >>= 1) a += __shfl_down(a, off, 64);
    if ((tid & 63) == 0) red[tid >> 6] = a;
    __syncthreads();
    if (tid == 0) x0h[b * C_ + c] = red[0] + red[1] + red[2] + red[3];
}

// f0h[b,o] = (sum_i x0h[b,i]*w0[l,i,o]) / NF
__global__ void f0_kernel(const float* __restrict__ x0h, const float* __restrict__ w0,
                          int l, float* __restrict__ f0h) {
    int o = threadIdx.x, b = blockIdx.x;
    const float* w = w0 + (size_t)l * C_ * C_;
    float a = 0.f;
    for (int i = 0; i < C_; ++i) a += x0h[b * C_ + i] * w[i * C_ + o];
    f0h[b * C_ + o] = a * (1.0f / NF_);
}

// fch'[b,o,k] = (2/NF) * sum_i (xch*wc - xsh*ws) ; fsh' = (2/NF)*sum_i (xsh*wc + xch*ws)
__global__ __launch_bounds__(256) void mix_kernel(const float* __restrict__ xch,
        const float* __restrict__ xsh, const float* __restrict__ wc,
        const float* __restrict__ ws, int l, float* __restrict__ fch,
        float* __restrict__ fsh) {
    int tid = threadIdx.x;
    int k = blockIdx.x * 64 + (tid & 63);
    int og = tid >> 6;
    int o0 = blockIdx.y * 8 + og * 2;
    const float* wcb = wc + (size_t)l * C_ * C_ * K_;
    const float* wsb = ws + (size_t)l * C_ * C_ * K_;
    float fc[2][4] = {{0}}, fs[2][4] = {{0}};
    for (int i = 0; i < C_; ++i) {
        float wc0 = wcb[((size_t)i * C_ + o0) * K_ + k];
        float wc1 = wcb[((size_t)i * C_ + o0 + 1) * K_ + k];
        float ws0 = wsb[((size_t)i * C_ + o0) * K_ + k];
        float ws1 = wsb[((size_t)i * C_ + o0 + 1) * K_ + k];
        for (int b = 0; b < 4; ++b) {
            float xc = xch[((size_t)b * C_ + i) * K_ + k];
            float xs = xsh[((size_t)b * C_ + i) * K_ + k];
            fc[0][b] += xc * wc0 - xs * ws0;
            fc[1][b] += xc * wc1 - xs * ws1;
            fs[0][b] += xs * wc0 + xc * ws0;
            fs[1][b] += xs * wc1 + xc * ws1;
        }
    }
    const float sc = 2.0f / NF_;
    for (int u = 0; u < 2; ++u)
        for (int b = 0; b < 4; ++b) {
            fch[((size_t)b * C_ + o0 + u) * K_ + k] = fc[u][b] * sc;
            fsh[((size_t)b * C_ + o0 + u) * K_ + k] = fs[u][b] * sc;
        }
}

// hnext[b,o,n] = f0h + sum_k(fch'*cos - fsh'*sin) + conv(h) + conv_b  (+gelu)
__global__ __launch_bounds__(256) void inv_kernel(const float* __restrict__ fch,
        const float* __restrict__ fsh, const float* __restrict__ cosv,
        const float* __restrict__ sinv, const float* __restrict__ hcur,
        const float* __restrict__ conv_w, const float* __restrict__ conv_b,
        const float* __restrict__ f0h, int l, int last, float* __restrict__ hnext) {
    __shared__ __align__(16) float A1[64 * 36];
    __shared__ __align__(16) float A2[64 * 36];
    __shared__ __align__(16) float Bt1[64 * 36];
    __shared__ __align__(16) float Bt2[64 * 36];
    int tid = threadIdx.x;
    int n0 = blockIdx.x * 64, o0 = blockIdx.y * 64, b = blockIdx.z;
    int tx = tid & 15, ty = tid >> 4;
    int srow = tid >> 3, skg = tid & 7;
    int tng = tid >> 4, tkr = tid & 15;
    float acc[4][4] = {{0}};
    // phase A: spectral part, reduce over K
    for (int kc = 0; kc < K_; kc += 32) {
        for (int pass = 0; pass < 2; ++pass) {
            int row = srow + pass * 32;
            *(float4*)&A1[row * 36 + skg * 4] =
                *(const float4*)&fch[((size_t)b * C_ + o0 + row) * K_ + kc + skg * 4];
            *(float4*)&A2[row * 36 + skg * 4] =
                *(const float4*)&fsh[((size_t)b * C_ + o0 + row) * K_ + kc + skg * 4];
            int krow = tkr + pass * 16;
            float4 cv = *(const float4*)&cosv[((size_t)b * K_ + kc + krow) * N_ + n0 + tng * 4];
            float4 sv = *(const float4*)&sinv[((size_t)b * K_ + kc + krow) * N_ + n0 + tng * 4];
            Bt1[(tng * 4 + 0) * 36 + krow] = cv.x; Bt1[(tng * 4 + 1) * 36 + krow] = cv.y;
            Bt1[(tng * 4 + 2) * 36 + krow] = cv.z; Bt1[(tng * 4 + 3) * 36 + krow] = cv.w;
            Bt2[(tng * 4 + 0) * 36 + krow] = sv.x; Bt2[(tng * 4 + 1) * 36 + krow] = sv.y;
            Bt2[(tng * 4 + 2) * 36 + krow] = sv.z; Bt2[(tng * 4 + 3) * 36 + krow] = sv.w;
        }
        __syncthreads();
        for (int kk = 0; kk < 32; kk += 4) {
            float4 ac[4], as[4], bc[4], bs[4];
            for (int i = 0; i < 4; ++i) {
                ac[i] = *(const float4*)&A1[(ty + 16 * i) * 36 + kk];
                as[i] = *(const float4*)&A2[(ty + 16 * i) * 36 + kk];
            }
            for (int j = 0; j < 4; ++j) {
                bc[j] = *(const float4*)&Bt1[(tx + 16 * j) * 36 + kk];
                bs[j] = *(const float4*)&Bt2[(tx + 16 * j) * 36 + kk];
            }
            for (int i = 0; i < 4; ++i)
                for (int j = 0; j < 4; ++j)
                    acc[i][j] += ac[i].x * bc[j].x - as[i].x * bs[j].x
                               + ac[i].y * bc[j].y - as[i].y * bs[j].y
                               + ac[i].z * bc[j].z - as[i].z * bs[j].z
                               + ac[i].w * bc[j].w - as[i].w * bs[j].w;
        }
        __syncthreads();
    }
    // phase B: conv part, reduce over C
    for (int ic = 0; ic < C_; ic += 32) {
        for (int pass = 0; pass < 2; ++pass) {
            int row = srow + pass * 32;
            *(float4*)&A1[row * 36 + skg * 4] =
                *(const float4*)&conv_w[((size_t)l * C_ + o0 + row) * C_ + ic + skg * 4];
            int krow = tkr + pass * 16;
            float4 hv = *(const float4*)&hcur[((size_t)b * C_ + ic + krow) * N_ + n0 + tng * 4];
            Bt1[(tng * 4 + 0) * 36 + krow] = hv.x; Bt1[(tng * 4 + 1) * 36 + krow] = hv.y;
            Bt1[(tng * 4 + 2) * 36 + krow] = hv.z; Bt1[(tng * 4 + 3) * 36 + krow] = hv.w;
        }
        __syncthreads();
        for (int kk = 0; kk < 32; kk += 4) {
            float4 a[4], bb[4];
            for (int i = 0; i < 4; ++i) a[i] = *(const float4*)&A1[(ty + 16 * i) * 36 + kk];
            for (int j = 0; j < 4; ++j) bb[j] = *(const float4*)&Bt1[(tx + 16 * j) * 36 + kk];
            for (int i = 0; i < 4; ++i)
                for (int j = 0; j < 4; ++j)
                    acc[i][j] += a[i].x * bb[j].x + a[i].y * bb[j].y
                               + a[i].z * bb[j].z + a[i].w * bb[j].w;
        }
        __syncthreads();
    }
    for (int i = 0; i < 4; ++i) {
        int o = o0 + ty + 16 * i;
        float base = f0h[b * C_ + o] + conv_b[l * C_ + o];
        for (int j = 0; j < 4; ++j) {
            float v = acc[i][j] + base;
            if (!last) v = gelu_exact(v);
            hnext[((size_t)b * C_ + o) * N_ + n0 + tx + 16 * j] = v;
        }
    }
}

// out[b,n] = fc2( gelu( fc1( h[b,:,n] ) ) )
__global__ __launch_bounds__(128) void head_kernel(const float* __restrict__ h,
        const float* __restrict__ fc1_w, const float* __restrict__ fc1_b,
        const float* __restrict__ fc2_w, const float* __restrict__ fc2_b,
        float* __restrict__ out) {
    int j = threadIdx.x;
    int bn = blockIdx.x;
    int b = bn >> 12;
    int n = bn & (N_ - 1);
    const float* hp = h + (size_t)b * C_ * N_ + n;
    float a = fc1_b[j];
    for (int c = 0; c < C_; ++c) a += hp[(size_t)c * N_] * fc1_w[c * FCD_ + j];
    a = gelu_exact(a);
    float v = a * fc2_w[j];
    for (int off = 32; off; off >>= 1) v += __shfl_down(v, off, 64);
    __shared__ float red[2];
    if ((j & 63) == 0) red[j >> 6] = v;
    __syncthreads();
    if (j == 0) out[bn] = red[0] + red[1] + fc2_b[0];
}

extern "C" void kernel_launch(void* const* d_in, const int* in_sizes, int n_in,
                              void* d_out, int out_size, void* d_ws, size_t ws_size,
                              hipStream_t stream) {
    const float* x      = (const float*)d_in[0];
    const float* xf     = (const float*)d_in[1];
    const int*   ind    = (const int*)d_in[2];
    const float* modes  = (const float*)d_in[3];
    const float* fc0_w  = (const float*)d_in[4];
    const float* fc0_b  = (const float*)d_in[5];
    const float* wc     = (const float*)d_in[6];
    const float* ws     = (const float*)d_in[7];
    const float* w0     = (const float*)d_in[8];
    const float* conv_w = (const float*)d_in[9];
    const float* conv_b = (const float*)d_in[10];
    const float* fc1_w  = (const float*)d_in[11];
    const float* fc1_b  = (const float*)d_in[12];
    const float* fc2_w  = (const float*)d_in[13];
    const float* fc2_b  = (const float*)d_in[14];
    float* out = (float*)d_out;

    float* wsf  = (float*)d_ws;
    float* cosv = wsf + COSV_OFF;
    float* sinv = wsf + SINV_OFF;
    float* h    = wsf + H_OFF;
    float* h2   = wsf + H2_OFF;
    float* wqn  = wsf + WQN_OFF;
    float* xch  = wsf + XCH_OFF;
    float* xsh  = wsf + XSH_OFF;
    float* fch  = wsf + FCH_OFF;
    float* fsh  = wsf + FSH_OFF;
    float* x0h  = wsf + X0_OFF;
    float* f0h  = wsf + F0_OFF;
    float* xcp  = wsf + XCP_OFF;
    float* xsp  = wsf + XSP_OFF;

    prep_kernel<<<dim3(N_ / 256, C_, B_), 256, 0, stream>>>(x, xf, ind, fc0_w, fc0_b, h, wqn);
    bases_kernel<<<dim3(N_ / 256, K_, B_), 256, 0, stream>>>(xf, ind, modes, cosv, sinv);

    float* cur = h;
    float* nxt = h2;
    for (int l = 0; l < L_; ++l) {
        fwd_gemm<<<dim3(K_ / 64, C_ / 64, B_ * 4), 256, 0, stream>>>(cur, wqn, cosv, sinv, xcp, xsp);
        red_kernel<<<dim3(B_ * C_ * K_ / 256), 256, 0, stream>>>(xcp, xsp, xch, xsh);
        x0_kernel<<<dim3(C_, B_), 256, 0, stream>>>(cur, wqn, x0h);
        f0_kernel<<<dim3(B_), C_, 0, stream>>>(x0h, w0, l, f0h);
        mix_kernel<<<dim3(K_ / 64, C_ / 8), 256, 0, stream>>>(xch, xsh, wc, ws, l, fch, fsh);
        inv_kernel<<<dim3(N_ / 64, C_ / 64, B_), 256, 0, stream>>>(fch, fsh, cosv, sinv, cur,
                                                                   conv_w, conv_b, f0h, l,
                                                                   (l == L_ - 1) ? 1 : 0, nxt);
        float* t = cur; cur = nxt; nxt = t;
    }
    head_kernel<<<dim3(B_ * N_), 128, 0, stream>>>(cur, fc1_w, fc1_b, fc2_w, fc2_b, out);
}

// Round 2
// 1480.739 us; speedup vs baseline: 1.0419x; 1.0419x over previous
//
#include <hip/hip_runtime.h>
#include <cmath>

#define B_ 4
#define N_ 4096
#define NF_ 8192
#define K_ 512
#define C_ 128
#define L_ 4
#define FCD_ 128
#define SPLIT_ 16

// ---- workspace layout (float offsets) ----
static const size_t COSV_OFF = 0;                               // B*K*N
static const size_t SINV_OFF = COSV_OFF + (size_t)B_*K_*N_;     // B*K*N
static const size_t H_OFF    = SINV_OFF + (size_t)B_*K_*N_;     // B*C*N
static const size_t H2_OFF   = H_OFF    + (size_t)B_*C_*N_;     // B*C*N
static const size_t WQN_OFF  = H2_OFF   + (size_t)B_*C_*N_;     // B*N
static const size_t XCH_OFF  = WQN_OFF  + (size_t)B_*N_;        // B*C*K
static const size_t XSH_OFF  = XCH_OFF  + (size_t)B_*C_*K_;
static const size_t FCH_OFF  = XSH_OFF  + (size_t)B_*C_*K_;
static const size_t FSH_OFF  = FCH_OFF  + (size_t)B_*C_*K_;
static const size_t X0_OFF   = FSH_OFF  + (size_t)B_*C_*K_;     // B*C
static const size_t F0_OFF   = X0_OFF   + (size_t)B_*C_;        // B*C
static const size_t XCP_OFF  = F0_OFF   + (size_t)B_*C_;        // SPLIT*B*C*K
static const size_t XSP_OFF  = XCP_OFF  + (size_t)SPLIT_*B_*C_*K_;
// inv partials alias the (dead-by-then) XCP region: 2 * B*C*N floats needed,
// XCP region alone is SPLIT*B*C*K = 4.19M >= 2*B*C*N = 4.19M.  exact fit.
static const size_t IPART_OFF = XCP_OFF;

__device__ __forceinline__ float gelu_exact(float v) {
    return v * 0.5f * (1.0f + erff(v * 0.70710678118654752440f));
}

// h[b,c,n] = fc0(x);  wqn[b,n] = wq[b,ind[n]] * N
__global__ void prep_kernel(const float* __restrict__ x, const float* __restrict__ xf,
                            const int* __restrict__ ind, const float* __restrict__ fc0_w,
                            const float* __restrict__ fc0_b, float* __restrict__ h,
                            float* __restrict__ wqn) {
    int n = blockIdx.x * 256 + threadIdx.x;
    int c = blockIdx.y;
    int b = blockIdx.z;
    const float* xp = x + ((size_t)b * N_ + n) * 3;
    float acc = fc0_b[c] + xp[0] * fc0_w[0 * C_ + c] + xp[1] * fc0_w[1 * C_ + c]
              + xp[2] * fc0_w[2 * C_ + c];
    h[((size_t)b * C_ + c) * N_ + n] = acc;
    if (c == 0) {
        int g = ind[n];
        wqn[b * N_ + n] = xf[((size_t)b * NF_ + g) * 4 + 2] * (float)N_;
    }
}

// cosv/sinv[b,k,n] at gathered grid points
__global__ void bases_kernel(const float* __restrict__ xf, const int* __restrict__ ind,
                             const float* __restrict__ modes, float* __restrict__ cosv,
                             float* __restrict__ sinv) {
    int n = blockIdx.x * 256 + threadIdx.x;
    int k = blockIdx.y;
    int b = blockIdx.z;
    int g = ind[n];
    float gx = xf[((size_t)b * NF_ + g) * 4 + 0];
    float gy = xf[((size_t)b * NF_ + g) * 4 + 1];
    float t = gx * modes[k * 2 + 0] + gy * modes[k * 2 + 1];
    float s, c;
    sincosf(t, &s, &c);
    size_t o = ((size_t)b * K_ + k) * N_ + n;
    cosv[o] = c;
    sinv[o] = s;
}

// xch_part[p,b,c,k] = sum_{n in chunk p} h*wqn*cos ; xsh_part = -sum h*wqn*sin
// SPLIT_=16 n-chunks of 256 -> 1024 blocks (4/CU, 16 waves/CU)
__global__ __launch_bounds__(256) void fwd_gemm(const float* __restrict__ h,
        const float* __restrict__ wqn, const float* __restrict__ cosv,
        const float* __restrict__ sinv, float* __restrict__ xcp, float* __restrict__ xsp) {
    __shared__ __align__(16) float hA[64 * 36];
    __shared__ __align__(16) float cB[64 * 36];
    __shared__ __align__(16) float sB[64 * 36];
    int tid = threadIdx.x;
    int k0 = blockIdx.x * 64, c0 = blockIdx.y * 64;
    int b = blockIdx.z >> 4, p = blockIdx.z & 15;
    int tx = tid & 15, ty = tid >> 4;
    int srow = tid >> 3, skg = tid & 7;
    float accC[4][4] = {{0}}, accS[4][4] = {{0}};
    const float* hb = h + ((size_t)b * C_ + c0) * N_;
    const float* cb = cosv + ((size_t)b * K_ + k0) * N_;
    const float* sb = sinv + ((size_t)b * K_ + k0) * N_;
    const float* wq = wqn + b * N_;
    for (int it = 0; it < 8; ++it) {
        int n0 = p * 256 + it * 32;
        for (int pass = 0; pass < 2; ++pass) {
            int row = srow + pass * 32;
            int nn4 = skg * 4;
            float4 wv = *(const float4*)&wq[n0 + nn4];
            float4 hv = *(const float4*)&hb[(size_t)row * N_ + n0 + nn4];
            hv.x *= wv.x; hv.y *= wv.y; hv.z *= wv.z; hv.w *= wv.w;
            *(float4*)&hA[row * 36 + nn4] = hv;
            *(float4*)&cB[row * 36 + nn4] = *(const float4*)&cb[(size_t)row * N_ + n0 + nn4];
            *(float4*)&sB[row * 36 + nn4] = *(const float4*)&sb[(size_t)row * N_ + n0 + nn4];
        }
        __syncthreads();
        for (int nn = 0; nn < 32; nn += 4) {
            float4 a[4], vc[4], vs[4];
            for (int i = 0; i < 4; ++i) a[i] = *(const float4*)&hA[(ty + 16 * i) * 36 + nn];
            for (int j = 0; j < 4; ++j) {
                vc[j] = *(const float4*)&cB[(tx + 16 * j) * 36 + nn];
                vs[j] = *(const float4*)&sB[(tx + 16 * j) * 36 + nn];
            }
            for (int i = 0; i < 4; ++i)
                for (int j = 0; j < 4; ++j) {
                    accC[i][j] += a[i].x * vc[j].x + a[i].y * vc[j].y
                                + a[i].z * vc[j].z + a[i].w * vc[j].w;
                    accS[i][j] += a[i].x * vs[j].x + a[i].y * vs[j].y
                                + a[i].z * vs[j].z + a[i].w * vs[j].w;
                }
        }
        __syncthreads();
    }
    size_t pb = (size_t)p * B_ + b;
    for (int i = 0; i < 4; ++i) {
        int c = c0 + ty + 16 * i;
        for (int j = 0; j < 4; ++j) {
            int k = k0 + tx + 16 * j;
            xcp[(pb * C_ + c) * K_ + k] = accC[i][j];
            xsp[(pb * C_ + c) * K_ + k] = -accS[i][j];
        }
    }
}

__global__ void red_kernel(const float* __restrict__ xcp, const float* __restrict__ xsp,
                           float* __restrict__ xch, float* __restrict__ xsh) {
    int t = blockIdx.x * 256 + threadIdx.x;
    const int BCK = B_ * C_ * K_;
    float a = 0.f, s = 0.f;
    for (int p = 0; p < SPLIT_; ++p) {
        a += xcp[(size_t)p * BCK + t];
        s += xsp[(size_t)p * BCK + t];
    }
    xch[t] = a; xsh[t] = s;
}

// x0h[b,c] = sum_n h*wqn
__global__ void x0_kernel(const float* __restrict__ h, const float* __restrict__ wqn,
                          float* __restrict__ x0h) {
    int c = blockIdx.x, b = blockIdx.y;
    int tid = threadIdx.x;
    const float* hp = h + ((size_t)b * C_ + c) * N_;
    const float* wq = wqn + b * N_;
    float a = 0.f;
    for (int n = tid; n < N_; n += 256) a += hp[n] * wq[n];
    __shared__ float red[4];
    for (int off = 32; off; off >>= 1) a += __shfl_down(a, off, 64);
    if ((tid & 63) == 0) red[tid >> 6] = a;
    __syncthreads();
    if (tid == 0) x0h[b * C_ + c] = red[0] + red[1] + red[2] + red[3];
}

// f0h[b,o] = (sum_i x0h[b,i]*w0[l,i,o]) / NF
__global__ void f0_kernel(const float* __restrict__ x0h, const float* __restrict__ w0,
                          int l, float* __restrict__ f0h) {
    int o = threadIdx.x, b = blockIdx.x;
    const float* w = w0 + (size_t)l * C_ * C_;
    float a = 0.f;
    for (int i = 0; i < C_; ++i) a += x0h[b * C_ + i] * w[i * C_ + o];
    f0h[b * C_ + o] = a * (1.0f / NF_);
}

// fch'[b,o,k] = (2/NF) * sum_i (xch*wc - xsh*ws) ; fsh' = (2/NF)*sum_i (xsh*wc + xch*ws)
// grid (K/64, C/4) = 256 blocks; 1 (o,k) per thread x 4 batches
__global__ __launch_bounds__(256) void mix_kernel(const float* __restrict__ xch,
        const float* __restrict__ xsh, const float* __restrict__ wc,
        const float* __restrict__ ws, int l, float* __restrict__ fch,
        float* __restrict__ fsh) {
    int tid = threadIdx.x;
    int k = blockIdx.x * 64 + (tid & 63);
    int o = blockIdx.y * 4 + (tid >> 6);
    const float* wcb = wc + (size_t)l * C_ * C_ * K_ + (size_t)o * K_ + k;
    const float* wsb = ws + (size_t)l * C_ * C_ * K_ + (size_t)o * K_ + k;
    float fc[4] = {0, 0, 0, 0}, fs[4] = {0, 0, 0, 0};
#pragma unroll 4
    for (int i = 0; i < C_; ++i) {
        float wci = wcb[(size_t)i * C_ * K_];
        float wsi = wsb[(size_t)i * C_ * K_];
        for (int b = 0; b < 4; ++b) {
            float xc = xch[((size_t)b * C_ + i) * K_ + k];
            float xs = xsh[((size_t)b * C_ + i) * K_ + k];
            fc[b] += xc * wci - xs * wsi;
            fs[b] += xs * wci + xc * wsi;
        }
    }
    const float sc = 2.0f / NF_;
    for (int b = 0; b < 4; ++b) {
        fch[((size_t)b * C_ + o) * K_ + k] = fc[b] * sc;
        fsh[((size_t)b * C_ + o) * K_ + k] = fs[b] * sc;
    }
}

// partial inverse: half hh reduces K in [hh*256, hh*256+256) and conv-C in
// [hh*64, hh*64+64).  P[hh][b][o][n] = partial sum (no bias/f0h/gelu).
// grid (N/64, C/64, B*2) = 1024 blocks
__global__ __launch_bounds__(256) void inv_part(const float* __restrict__ fch,
        const float* __restrict__ fsh, const float* __restrict__ cosv,
        const float* __restrict__ sinv, const float* __restrict__ hcur,
        const float* __restrict__ conv_w, int l, float* __restrict__ P) {
    __shared__ __align__(16) float A1[64 * 36];
    __shared__ __align__(16) float A2[64 * 36];
    __shared__ __align__(16) float Bt1[64 * 36];
    __shared__ __align__(16) float Bt2[64 * 36];
    int tid = threadIdx.x;
    int n0 = blockIdx.x * 64, o0 = blockIdx.y * 64;
    int b = blockIdx.z >> 1, hh = blockIdx.z & 1;
    int tx = tid & 15, ty = tid >> 4;
    int srow = tid >> 3, skg = tid & 7;
    int tng = tid >> 4, tkr = tid & 15;
    float acc[4][4] = {{0}};
    // phase A: spectral part, reduce over this half's K range
    int kbeg = hh * 256, kend = kbeg + 256;
    for (int kc = kbeg; kc < kend; kc += 32) {
        for (int pass = 0; pass < 2; ++pass) {
            int row = srow + pass * 32;
            *(float4*)&A1[row * 36 + skg * 4] =
                *(const float4*)&fch[((size_t)b * C_ + o0 + row) * K_ + kc + skg * 4];
            *(float4*)&A2[row * 36 + skg * 4] =
                *(const float4*)&fsh[((size_t)b * C_ + o0 + row) * K_ + kc + skg * 4];
            int krow = tkr + pass * 16;
            float4 cv = *(const float4*)&cosv[((size_t)b * K_ + kc + krow) * N_ + n0 + tng * 4];
            float4 sv = *(const float4*)&sinv[((size_t)b * K_ + kc + krow) * N_ + n0 + tng * 4];
            Bt1[(tng * 4 + 0) * 36 + krow] = cv.x; Bt1[(tng * 4 + 1) * 36 + krow] = cv.y;
            Bt1[(tng * 4 + 2) * 36 + krow] = cv.z; Bt1[(tng * 4 + 3) * 36 + krow] = cv.w;
            Bt2[(tng * 4 + 0) * 36 + krow] = sv.x; Bt2[(tng * 4 + 1) * 36 + krow] = sv.y;
            Bt2[(tng * 4 + 2) * 36 + krow] = sv.z; Bt2[(tng * 4 + 3) * 36 + krow] = sv.w;
        }
        __syncthreads();
        for (int kk = 0; kk < 32; kk += 4) {
            float4 ac[4], as[4], bc[4], bs[4];
            for (int i = 0; i < 4; ++i) {
                ac[i] = *(const float4*)&A1[(ty + 16 * i) * 36 + kk];
                as[i] = *(const float4*)&A2[(ty + 16 * i) * 36 + kk];
            }
            for (int j = 0; j < 4; ++j) {
                bc[j] = *(const float4*)&Bt1[(tx + 16 * j) * 36 + kk];
                bs[j] = *(const float4*)&Bt2[(tx + 16 * j) * 36 + kk];
            }
            for (int i = 0; i < 4; ++i)
                for (int j = 0; j < 4; ++j)
                    acc[i][j] += ac[i].x * bc[j].x - as[i].x * bs[j].x
                               + ac[i].y * bc[j].y - as[i].y * bs[j].y
                               + ac[i].z * bc[j].z - as[i].z * bs[j].z
                               + ac[i].w * bc[j].w - as[i].w * bs[j].w;
        }
        __syncthreads();
    }
    // phase B: conv part, reduce over this half's C range
    int ibeg = hh * 64, iend = ibeg + 64;
    for (int ic = ibeg; ic < iend; ic += 32) {
        for (int pass = 0; pass < 2; ++pass) {
            int row = srow + pass * 32;
            *(float4*)&A1[row * 36 + skg * 4] =
                *(const float4*)&conv_w[((size_t)l * C_ + o0 + row) * C_ + ic + skg * 4];
            int krow = tkr + pass * 16;
            float4 hv = *(const float4*)&hcur[((size_t)b * C_ + ic + krow) * N_ + n0 + tng * 4];
            Bt1[(tng * 4 + 0) * 36 + krow] = hv.x; Bt1[(tng * 4 + 1) * 36 + krow] = hv.y;
            Bt1[(tng * 4 + 2) * 36 + krow] = hv.z; Bt1[(tng * 4 + 3) * 36 + krow] = hv.w;
        }
        __syncthreads();
        for (int kk = 0; kk < 32; kk += 4) {
            float4 a[4], bb[4];
            for (int i = 0; i < 4; ++i) a[i] = *(const float4*)&A1[(ty + 16 * i) * 36 + kk];
            for (int j = 0; j < 4; ++j) bb[j] = *(const float4*)&Bt1[(tx + 16 * j) * 36 + kk];
            for (int i = 0; i < 4; ++i)
                for (int j = 0; j < 4; ++j)
                    acc[i][j] += a[i].x * bb[j].x + a[i].y * bb[j].y
                               + a[i].z * bb[j].z + a[i].w * bb[j].w;
        }
        __syncthreads();
    }
    float* Po = P + (size_t)hh * B_ * C_ * N_;
    for (int i = 0; i < 4; ++i) {
        int o = o0 + ty + 16 * i;
        for (int j = 0; j < 4; ++j)
            Po[((size_t)b * C_ + o) * N_ + n0 + tx + 16 * j] = acc[i][j];
    }
}

// hnext = gelu?(P0 + P1 + f0h[b,o] + conv_b[l,o])
__global__ void combine_kernel(const float* __restrict__ P, const float* __restrict__ f0h,
                               const float* __restrict__ conv_b, int l, int last,
                               float* __restrict__ hnext) {
    int t = blockIdx.x * 256 + threadIdx.x;   // over B*C*N
    int bc = t >> 12;                          // b*C + o   (N=4096)
    int o = bc & (C_ - 1);
    float v = P[t] + P[(size_t)B_ * C_ * N_ + t] + f0h[bc] + conv_b[l * C_ + o];
    if (!last) v = gelu_exact(v);
    hnext[t] = v;
}

// out[b,n] = fc2( gelu( fc1( h[b,:,n] ) ) )
__global__ __launch_bounds__(128) void head_kernel(const float* __restrict__ h,
        const float* __restrict__ fc1_w, const float* __restrict__ fc1_b,
        const float* __restrict__ fc2_w, const float* __restrict__ fc2_b,
        float* __restrict__ out) {
    int j = threadIdx.x;
    int bn = blockIdx.x;
    int b = bn >> 12;
    int n = bn & (N_ - 1);
    const float* hp = h + (size_t)b * C_ * N_ + n;
    float a = fc1_b[j];
    for (int c = 0; c < C_; ++c) a += hp[(size_t)c * N_] * fc1_w[c * FCD_ + j];
    a = gelu_exact(a);
    float v = a * fc2_w[j];
    for (int off = 32; off; off >>= 1) v += __shfl_down(v, off, 64);
    __shared__ float red[2];
    if ((j & 63) == 0) red[j >> 6] = v;
    __syncthreads();
    if (j == 0) out[bn] = red[0] + red[1] + fc2_b[0];
}

extern "C" void kernel_launch(void* const* d_in, const int* in_sizes, int n_in,
                              void* d_out, int out_size, void* d_ws, size_t ws_size,
                              hipStream_t stream) {
    const float* x      = (const float*)d_in[0];
    const float* xf     = (const float*)d_in[1];
    const int*   ind    = (const int*)d_in[2];
    const float* modes  = (const float*)d_in[3];
    const float* fc0_w  = (const float*)d_in[4];
    const float* fc0_b  = (const float*)d_in[5];
    const float* wc     = (const float*)d_in[6];
    const float* ws     = (const float*)d_in[7];
    const float* w0     = (const float*)d_in[8];
    const float* conv_w = (const float*)d_in[9];
    const float* conv_b = (const float*)d_in[10];
    const float* fc1_w  = (const float*)d_in[11];
    const float* fc1_b  = (const float*)d_in[12];
    const float* fc2_w  = (const float*)d_in[13];
    const float* fc2_b  = (const float*)d_in[14];
    float* out = (float*)d_out;

    float* wsf  = (float*)d_ws;
    float* cosv = wsf + COSV_OFF;
    float* sinv = wsf + SINV_OFF;
    float* h    = wsf + H_OFF;
    float* h2   = wsf + H2_OFF;
    float* wqn  = wsf + WQN_OFF;
    float* xch  = wsf + XCH_OFF;
    float* xsh  = wsf + XSH_OFF;
    float* fch  = wsf + FCH_OFF;
    float* fsh  = wsf + FSH_OFF;
    float* x0h  = wsf + X0_OFF;
    float* f0h  = wsf + F0_OFF;
    float* xcp  = wsf + XCP_OFF;
    float* xsp  = wsf + XSP_OFF;
    float* ipart = wsf + IPART_OFF;

    prep_kernel<<<dim3(N_ / 256, C_, B_), 256, 0, stream>>>(x, xf, ind, fc0_w, fc0_b, h, wqn);
    bases_kernel<<<dim3(N_ / 256, K_, B_), 256, 0, stream>>>(xf, ind, modes, cosv, sinv);

    float* cur = h;
    float* nxt = h2;
    for (int l = 0; l < L_; ++l) {
        fwd_gemm<<<dim3(K_ / 64, C_ / 64, B_ * SPLIT_), 256, 0, stream>>>(cur, wqn, cosv, sinv,
                                                                          xcp, xsp);
        red_kernel<<<dim3(B_ * C_ * K_ / 256), 256, 0, stream>>>(xcp, xsp, xch, xsh);
        x0_kernel<<<dim3(C_, B_), 256, 0, stream>>>(cur, wqn, x0h);
        f0_kernel<<<dim3(B_), C_, 0, stream>>>(x0h, w0, l, f0h);
        mix_kernel<<<dim3(K_ / 64, C_ / 4), 256, 0, stream>>>(xch, xsh, wc, ws, l, fch, fsh);
        inv_part<<<dim3(N_ / 64, C_ / 64, B_ * 2), 256, 0, stream>>>(fch, fsh, cosv, sinv, cur,
                                                                     conv_w, l, ipart);
        combine_kernel<<<dim3(B_ * C_ * N_ / 256), 256, 0, stream>>>(ipart, f0h, conv_b, l,
                                                                     (l == L_ - 1) ? 1 : 0, nxt);
        float* t = cur; cur = nxt; nxt = t;
    }
    head_kernel<<<dim3(B_ * N_), 128, 0, stream>>>(cur, fc1_w, fc1_b, fc2_w, fc2_b, out);
}

// Round 3
// 1225.468 us; speedup vs baseline: 1.2589x; 1.2083x over previous
//
#include <hip/hip_runtime.h>
#include <cmath>

#define B_ 4
#define N_ 4096
#define NF_ 8192
#define K_ 512
#define C_ 128
#define L_ 4
#define FCD_ 128
#define SPLIT_ 16

// ---- workspace layout (float offsets) ----
static const size_t COSV_OFF = 0;                               // B*K*N
static const size_t SINV_OFF = COSV_OFF + (size_t)B_*K_*N_;     // B*K*N
static const size_t H_OFF    = SINV_OFF + (size_t)B_*K_*N_;     // B*C*N
static const size_t H2_OFF   = H_OFF    + (size_t)B_*C_*N_;     // B*C*N
static const size_t WQN_OFF  = H2_OFF   + (size_t)B_*C_*N_;     // B*N
static const size_t XCH_OFF  = WQN_OFF  + (size_t)B_*N_;        // B*C*K
static const size_t XSH_OFF  = XCH_OFF  + (size_t)B_*C_*K_;
static const size_t FCH_OFF  = XSH_OFF  + (size_t)B_*C_*K_;
static const size_t FSH_OFF  = FCH_OFF  + (size_t)B_*C_*K_;
static const size_t X0_OFF   = FSH_OFF  + (size_t)B_*C_*K_;     // B*C
static const size_t F0_OFF   = X0_OFF   + (size_t)B_*C_;        // B*C
static const size_t XCP_OFF  = F0_OFF   + (size_t)B_*C_;        // SPLIT*B*C*K
static const size_t XSP_OFF  = XCP_OFF  + (size_t)SPLIT_*B_*C_*K_;
// inv partials alias the (dead-by-then) XCP region: 2 * B*C*N floats needed.
static const size_t IPART_OFF = XCP_OFF;

__device__ __forceinline__ float gelu_exact(float v) {
    return v * 0.5f * (1.0f + erff(v * 0.70710678118654752440f));
}

// h[b,c,n] = fc0(x);  wqn[b,n] = wq[b,ind[n]] * N
__global__ void prep_kernel(const float* __restrict__ x, const float* __restrict__ xf,
                            const int* __restrict__ ind, const float* __restrict__ fc0_w,
                            const float* __restrict__ fc0_b, float* __restrict__ h,
                            float* __restrict__ wqn) {
    int n = blockIdx.x * 256 + threadIdx.x;
    int c = blockIdx.y;
    int b = blockIdx.z;
    const float* xp = x + ((size_t)b * N_ + n) * 3;
    float acc = fc0_b[c] + xp[0] * fc0_w[0 * C_ + c] + xp[1] * fc0_w[1 * C_ + c]
              + xp[2] * fc0_w[2 * C_ + c];
    h[((size_t)b * C_ + c) * N_ + n] = acc;
    if (c == 0) {
        int g = ind[n];
        wqn[b * N_ + n] = xf[((size_t)b * NF_ + g) * 4 + 2] * (float)N_;
    }
}

// cosv/sinv[b,k,n] at gathered grid points
__global__ void bases_kernel(const float* __restrict__ xf, const int* __restrict__ ind,
                             const float* __restrict__ modes, float* __restrict__ cosv,
                             float* __restrict__ sinv) {
    int n = blockIdx.x * 256 + threadIdx.x;
    int k = blockIdx.y;
    int b = blockIdx.z;
    int g = ind[n];
    float gx = xf[((size_t)b * NF_ + g) * 4 + 0];
    float gy = xf[((size_t)b * NF_ + g) * 4 + 1];
    float t = gx * modes[k * 2 + 0] + gy * modes[k * 2 + 1];
    float s, c;
    sincosf(t, &s, &c);
    size_t o = ((size_t)b * K_ + k) * N_ + n;
    cosv[o] = c;
    sinv[o] = s;
}

// xch_part[p,b,c,k] = sum_{n in chunk p} h*wqn*cos ; xsh_part = -sum h*wqn*sin
__global__ __launch_bounds__(256) void fwd_gemm(const float* __restrict__ h,
        const float* __restrict__ wqn, const float* __restrict__ cosv,
        const float* __restrict__ sinv, float* __restrict__ xcp, float* __restrict__ xsp) {
    __shared__ __align__(16) float hA[64 * 36];
    __shared__ __align__(16) float cB[64 * 36];
    __shared__ __align__(16) float sB[64 * 36];
    int tid = threadIdx.x;
    int k0 = blockIdx.x * 64, c0 = blockIdx.y * 64;
    int b = blockIdx.z >> 4, p = blockIdx.z & 15;
    int tx = tid & 15, ty = tid >> 4;
    int srow = tid >> 3, skg = tid & 7;
    float accC[4][4] = {{0}}, accS[4][4] = {{0}};
    const float* hb = h + ((size_t)b * C_ + c0) * N_;
    const float* cb = cosv + ((size_t)b * K_ + k0) * N_;
    const float* sb = sinv + ((size_t)b * K_ + k0) * N_;
    const float* wq = wqn + b * N_;
    for (int it = 0; it < 8; ++it) {
        int n0 = p * 256 + it * 32;
        for (int pass = 0; pass < 2; ++pass) {
            int row = srow + pass * 32;
            int nn4 = skg * 4;
            float4 wv = *(const float4*)&wq[n0 + nn4];
            float4 hv = *(const float4*)&hb[(size_t)row * N_ + n0 + nn4];
            hv.x *= wv.x; hv.y *= wv.y; hv.z *= wv.z; hv.w *= wv.w;
            *(float4*)&hA[row * 36 + nn4] = hv;
            *(float4*)&cB[row * 36 + nn4] = *(const float4*)&cb[(size_t)row * N_ + n0 + nn4];
            *(float4*)&sB[row * 36 + nn4] = *(const float4*)&sb[(size_t)row * N_ + n0 + nn4];
        }
        __syncthreads();
        for (int nn = 0; nn < 32; nn += 4) {
            float4 a[4], vc[4], vs[4];
            for (int i = 0; i < 4; ++i) a[i] = *(const float4*)&hA[(ty + 16 * i) * 36 + nn];
            for (int j = 0; j < 4; ++j) {
                vc[j] = *(const float4*)&cB[(tx + 16 * j) * 36 + nn];
                vs[j] = *(const float4*)&sB[(tx + 16 * j) * 36 + nn];
            }
            for (int i = 0; i < 4; ++i)
                for (int j = 0; j < 4; ++j) {
                    accC[i][j] += a[i].x * vc[j].x + a[i].y * vc[j].y
                                + a[i].z * vc[j].z + a[i].w * vc[j].w;
                    accS[i][j] += a[i].x * vs[j].x + a[i].y * vs[j].y
                                + a[i].z * vs[j].z + a[i].w * vs[j].w;
                }
        }
        __syncthreads();
    }
    size_t pb = (size_t)p * B_ + b;
    for (int i = 0; i < 4; ++i) {
        int c = c0 + ty + 16 * i;
        for (int j = 0; j < 4; ++j) {
            int k = k0 + tx + 16 * j;
            xcp[(pb * C_ + c) * K_ + k] = accC[i][j];
            xsp[(pb * C_ + c) * K_ + k] = -accS[i][j];
        }
    }
}

__global__ void red_kernel(const float* __restrict__ xcp, const float* __restrict__ xsp,
                           float* __restrict__ xch, float* __restrict__ xsh) {
    int t = blockIdx.x * 256 + threadIdx.x;
    const int BCK = B_ * C_ * K_;
    float a = 0.f, s = 0.f;
    for (int p = 0; p < SPLIT_; ++p) {
        a += xcp[(size_t)p * BCK + t];
        s += xsp[(size_t)p * BCK + t];
    }
    xch[t] = a; xsh[t] = s;
}

// x0h[b,c] = sum_n h*wqn
__global__ void x0_kernel(const float* __restrict__ h, const float* __restrict__ wqn,
                          float* __restrict__ x0h) {
    int c = blockIdx.x, b = blockIdx.y;
    int tid = threadIdx.x;
    const float* hp = h + ((size_t)b * C_ + c) * N_;
    const float* wq = wqn + b * N_;
    float a = 0.f;
    for (int n = tid; n < N_; n += 256) a += hp[n] * wq[n];
    __shared__ float red[4];
    for (int off = 32; off; off >>= 1) a += __shfl_down(a, off, 64);
    if ((tid & 63) == 0) red[tid >> 6] = a;
    __syncthreads();
    if (tid == 0) x0h[b * C_ + c] = red[0] + red[1] + red[2] + red[3];
}

// f0h[b,o] = (sum_i x0h[b,i]*w0[l,i,o]) / NF
__global__ void f0_kernel(const float* __restrict__ x0h, const float* __restrict__ w0,
                          int l, float* __restrict__ f0h) {
    int o = threadIdx.x, b = blockIdx.x;
    const float* w = w0 + (size_t)l * C_ * C_;
    float a = 0.f;
    for (int i = 0; i < C_; ++i) a += x0h[b * C_ + i] * w[i * C_ + o];
    f0h[b * C_ + o] = a * (1.0f / NF_);
}

// fch'[b,o,k] = (2/NF) * sum_i (xch*wc - xsh*ws) ; fsh' = (2/NF)*sum_i (xsh*wc + xch*ws)
// grid (K/64, C) = 1024 blocks.  64 lanes = k, 4 wave-groups split i (32 each),
// LDS cross-wave reduce (stride-5 pad).  Weight stream is compulsory 67 MB/layer.
__global__ __launch_bounds__(256) void mix_kernel(const float* __restrict__ xch,
        const float* __restrict__ xsh, const float* __restrict__ wc,
        const float* __restrict__ ws, int l, float* __restrict__ fch,
        float* __restrict__ fsh) {
    __shared__ float red[512 * 5];
    int tid = threadIdx.x;
    int lane = tid & 63;
    int g = tid >> 6;                // i-group (one wave each)
    int k = blockIdx.x * 64 + lane;
    int o = blockIdx.y;
    const float* wcb = wc + ((size_t)l * C_ * C_ + o) * K_ + k;   // + i*C*K
    const float* wsb = ws + ((size_t)l * C_ * C_ + o) * K_ + k;
    float fc[4] = {0, 0, 0, 0}, fs[4] = {0, 0, 0, 0};
    int i0 = g * 32;
#pragma unroll 4
    for (int ii = 0; ii < 32; ++ii) {
        int i = i0 + ii;
        float wci = wcb[(size_t)i * (C_ * K_)];
        float wsi = wsb[(size_t)i * (C_ * K_)];
#pragma unroll
        for (int b = 0; b < 4; ++b) {
            float xc = xch[((size_t)b * C_ + i) * K_ + k];
            float xs = xsh[((size_t)b * C_ + i) * K_ + k];
            fc[b] += xc * wci - xs * wsi;
            fs[b] += xs * wci + xc * wsi;
        }
    }
#pragma unroll
    for (int b = 0; b < 4; ++b) {
        red[((b * 2 + 0) * 64 + lane) * 5 + g] = fc[b];
        red[((b * 2 + 1) * 64 + lane) * 5 + g] = fs[b];
    }
    __syncthreads();
    const float sc = 2.0f / NF_;
    for (int v = tid; v < 512; v += 256) {
        float sum = red[v * 5 + 0] + red[v * 5 + 1] + red[v * 5 + 2] + red[v * 5 + 3];
        int lane2 = v & 63;
        int bs = v >> 6;             // b*2 + s
        int b = bs >> 1, s = bs & 1;
        float* dst = (s == 0) ? fch : fsh;
        dst[((size_t)b * C_ + o) * K_ + blockIdx.x * 64 + lane2] = sum * sc;
    }
}

// partial inverse: half hh reduces K in [hh*256, +256) and conv-C in [hh*64, +64)
__global__ __launch_bounds__(256) void inv_part(const float* __restrict__ fch,
        const float* __restrict__ fsh, const float* __restrict__ cosv,
        const float* __restrict__ sinv, const float* __restrict__ hcur,
        const float* __restrict__ conv_w, int l, float* __restrict__ P) {
    __shared__ __align__(16) float A1[64 * 36];
    __shared__ __align__(16) float A2[64 * 36];
    __shared__ __align__(16) float Bt1[64 * 36];
    __shared__ __align__(16) float Bt2[64 * 36];
    int tid = threadIdx.x;
    int n0 = blockIdx.x * 64, o0 = blockIdx.y * 64;
    int b = blockIdx.z >> 1, hh = blockIdx.z & 1;
    int tx = tid & 15, ty = tid >> 4;
    int srow = tid >> 3, skg = tid & 7;
    int tng = tid >> 4, tkr = tid & 15;
    float acc[4][4] = {{0}};
    int kbeg = hh * 256, kend = kbeg + 256;
    for (int kc = kbeg; kc < kend; kc += 32) {
        for (int pass = 0; pass < 2; ++pass) {
            int row = srow + pass * 32;
            *(float4*)&A1[row * 36 + skg * 4] =
                *(const float4*)&fch[((size_t)b * C_ + o0 + row) * K_ + kc + skg * 4];
            *(float4*)&A2[row * 36 + skg * 4] =
                *(const float4*)&fsh[((size_t)b * C_ + o0 + row) * K_ + kc + skg * 4];
            int krow = tkr + pass * 16;
            float4 cv = *(const float4*)&cosv[((size_t)b * K_ + kc + krow) * N_ + n0 + tng * 4];
            float4 sv = *(const float4*)&sinv[((size_t)b * K_ + kc + krow) * N_ + n0 + tng * 4];
            Bt1[(tng * 4 + 0) * 36 + krow] = cv.x; Bt1[(tng * 4 + 1) * 36 + krow] = cv.y;
            Bt1[(tng * 4 + 2) * 36 + krow] = cv.z; Bt1[(tng * 4 + 3) * 36 + krow] = cv.w;
            Bt2[(tng * 4 + 0) * 36 + krow] = sv.x; Bt2[(tng * 4 + 1) * 36 + krow] = sv.y;
            Bt2[(tng * 4 + 2) * 36 + krow] = sv.z; Bt2[(tng * 4 + 3) * 36 + krow] = sv.w;
        }
        __syncthreads();
        for (int kk = 0; kk < 32; kk += 4) {
            float4 ac[4], as[4], bc[4], bs[4];
            for (int i = 0; i < 4; ++i) {
                ac[i] = *(const float4*)&A1[(ty + 16 * i) * 36 + kk];
                as[i] = *(const float4*)&A2[(ty + 16 * i) * 36 + kk];
            }
            for (int j = 0; j < 4; ++j) {
                bc[j] = *(const float4*)&Bt1[(tx + 16 * j) * 36 + kk];
                bs[j] = *(const float4*)&Bt2[(tx + 16 * j) * 36 + kk];
            }
            for (int i = 0; i < 4; ++i)
                for (int j = 0; j < 4; ++j)
                    acc[i][j] += ac[i].x * bc[j].x - as[i].x * bs[j].x
                               + ac[i].y * bc[j].y - as[i].y * bs[j].y
                               + ac[i].z * bc[j].z - as[i].z * bs[j].z
                               + ac[i].w * bc[j].w - as[i].w * bs[j].w;
        }
        __syncthreads();
    }
    int ibeg = hh * 64, iend = ibeg + 64;
    for (int ic = ibeg; ic < iend; ic += 32) {
        for (int pass = 0; pass < 2; ++pass) {
            int row = srow + pass * 32;
            *(float4*)&A1[row * 36 + skg * 4] =
                *(const float4*)&conv_w[((size_t)l * C_ + o0 + row) * C_ + ic + skg * 4];
            int krow = tkr + pass * 16;
            float4 hv = *(const float4*)&hcur[((size_t)b * C_ + ic + krow) * N_ + n0 + tng * 4];
            Bt1[(tng * 4 + 0) * 36 + krow] = hv.x; Bt1[(tng * 4 + 1) * 36 + krow] = hv.y;
            Bt1[(tng * 4 + 2) * 36 + krow] = hv.z; Bt1[(tng * 4 + 3) * 36 + krow] = hv.w;
        }
        __syncthreads();
        for (int kk = 0; kk < 32; kk += 4) {
            float4 a[4], bb[4];
            for (int i = 0; i < 4; ++i) a[i] = *(const float4*)&A1[(ty + 16 * i) * 36 + kk];
            for (int j = 0; j < 4; ++j) bb[j] = *(const float4*)&Bt1[(tx + 16 * j) * 36 + kk];
            for (int i = 0; i < 4; ++i)
                for (int j = 0; j < 4; ++j)
                    acc[i][j] += a[i].x * bb[j].x + a[i].y * bb[j].y
                               + a[i].z * bb[j].z + a[i].w * bb[j].w;
        }
        __syncthreads();
    }
    float* Po = P + (size_t)hh * B_ * C_ * N_;
    for (int i = 0; i < 4; ++i) {
        int o = o0 + ty + 16 * i;
        for (int j = 0; j < 4; ++j)
            Po[((size_t)b * C_ + o) * N_ + n0 + tx + 16 * j] = acc[i][j];
    }
}

// hnext = gelu?(P0 + P1 + f0h[b,o] + conv_b[l,o])
__global__ void combine_kernel(const float* __restrict__ P, const float* __restrict__ f0h,
                               const float* __restrict__ conv_b, int l, int last,
                               float* __restrict__ hnext) {
    int t = blockIdx.x * 256 + threadIdx.x;   // over B*C*N
    int bc = t >> 12;                          // b*C + o   (N=4096)
    int o = bc & (C_ - 1);
    float v = P[t] + P[(size_t)B_ * C_ * N_ + t] + f0h[bc] + conv_b[l * C_ + o];
    if (!last) v = gelu_exact(v);
    hnext[t] = v;
}

// out[b,n] = fc2( gelu( fc1( h[b,:,n] ) ) )
__global__ __launch_bounds__(128) void head_kernel(const float* __restrict__ h,
        const float* __restrict__ fc1_w, const float* __restrict__ fc1_b,
        const float* __restrict__ fc2_w, const float* __restrict__ fc2_b,
        float* __restrict__ out) {
    int j = threadIdx.x;
    int bn = blockIdx.x;
    int b = bn >> 12;
    int n = bn & (N_ - 1);
    const float* hp = h + (size_t)b * C_ * N_ + n;
    float a = fc1_b[j];
    for (int c = 0; c < C_; ++c) a += hp[(size_t)c * N_] * fc1_w[c * FCD_ + j];
    a = gelu_exact(a);
    float v = a * fc2_w[j];
    for (int off = 32; off; off >>= 1) v += __shfl_down(v, off, 64);
    __shared__ float red[2];
    if ((j & 63) == 0) red[j >> 6] = v;
    __syncthreads();
    if (j == 0) out[bn] = red[0] + red[1] + fc2_b[0];
}

extern "C" void kernel_launch(void* const* d_in, const int* in_sizes, int n_in,
                              void* d_out, int out_size, void* d_ws, size_t ws_size,
                              hipStream_t stream) {
    const float* x      = (const float*)d_in[0];
    const float* xf     = (const float*)d_in[1];
    const int*   ind    = (const int*)d_in[2];
    const float* modes  = (const float*)d_in[3];
    const float* fc0_w  = (const float*)d_in[4];
    const float* fc0_b  = (const float*)d_in[5];
    const float* wc     = (const float*)d_in[6];
    const float* ws     = (const float*)d_in[7];
    const float* w0     = (const float*)d_in[8];
    const float* conv_w = (const float*)d_in[9];
    const float* conv_b = (const float*)d_in[10];
    const float* fc1_w  = (const float*)d_in[11];
    const float* fc1_b  = (const float*)d_in[12];
    const float* fc2_w  = (const float*)d_in[13];
    const float* fc2_b  = (const float*)d_in[14];
    float* out = (float*)d_out;

    float* wsf  = (float*)d_ws;
    float* cosv = wsf + COSV_OFF;
    float* sinv = wsf + SINV_OFF;
    float* h    = wsf + H_OFF;
    float* h2   = wsf + H2_OFF;
    float* wqn  = wsf + WQN_OFF;
    float* xch  = wsf + XCH_OFF;
    float* xsh  = wsf + XSH_OFF;
    float* fch  = wsf + FCH_OFF;
    float* fsh  = wsf + FSH_OFF;
    float* x0h  = wsf + X0_OFF;
    float* f0h  = wsf + F0_OFF;
    float* xcp  = wsf + XCP_OFF;
    float* xsp  = wsf + XSP_OFF;
    float* ipart = wsf + IPART_OFF;

    prep_kernel<<<dim3(N_ / 256, C_, B_), 256, 0, stream>>>(x, xf, ind, fc0_w, fc0_b, h, wqn);
    bases_kernel<<<dim3(N_ / 256, K_, B_), 256, 0, stream>>>(xf, ind, modes, cosv, sinv);

    float* cur = h;
    float* nxt = h2;
    for (int l = 0; l < L_; ++l) {
        fwd_gemm<<<dim3(K_ / 64, C_ / 64, B_ * SPLIT_), 256, 0, stream>>>(cur, wqn, cosv, sinv,
                                                                          xcp, xsp);
        red_kernel<<<dim3(B_ * C_ * K_ / 256), 256, 0, stream>>>(xcp, xsp, xch, xsh);
        x0_kernel<<<dim3(C_, B_), 256, 0, stream>>>(cur, wqn, x0h);
        f0_kernel<<<dim3(B_), C_, 0, stream>>>(x0h, w0, l, f0h);
        mix_kernel<<<dim3(K_ / 64, C_), 256, 0, stream>>>(xch, xsh, wc, ws, l, fch, fsh);
        inv_part<<<dim3(N_ / 64, C_ / 64, B_ * 2), 256, 0, stream>>>(fch, fsh, cosv, sinv, cur,
                                                                     conv_w, l, ipart);
        combine_kernel<<<dim3(B_ * C_ * N_ / 256), 256, 0, stream>>>(ipart, f0h, conv_b, l,
                                                                     (l == L_ - 1) ? 1 : 0, nxt);
        float* t = cur; cur = nxt; nxt = t;
    }
    head_kernel<<<dim3(B_ * N_), 128, 0, stream>>>(cur, fc1_w, fc1_b, fc2_w, fc2_b, out);
}

// Round 4
// 1018.388 us; speedup vs baseline: 1.5149x; 1.2033x over previous
//
#include <hip/hip_runtime.h>
#include <cmath>

#define B_ 4
#define N_ 4096
#define NF_ 8192
#define K_ 512
#define C_ 128
#define L_ 4
#define FCD_ 128
#define SPLIT_ 8

typedef _Float16 f16x8 __attribute__((ext_vector_type(8)));
typedef float f32x4 __attribute__((ext_vector_type(4)));

#define MFMA16(a, b, c) __builtin_amdgcn_mfma_f32_16x16x32_f16((a), (b), (c), 0, 0, 0)

static const float SPLIT_SCALE = 2048.0f;      // 2^11
static const float INV_SPLIT_SCALE = 1.0f / 2048.0f;

// ---- workspace layout (float offsets; f16 arrays use count/2 floats) ----
static const size_t SZ_CKN = (size_t)B_ * K_ * N_ / 2;   // one f16 [b][k][n] array
static const size_t SZ_CNK = (size_t)B_ * N_ * K_ / 2;   // one f16 [b][n][k] array
static const size_t SZ_H   = (size_t)B_ * C_ * N_;       // fp32
static const size_t SZ_HS  = (size_t)B_ * C_ * N_ / 2;   // f16 split
static const size_t SZ_FS  = (size_t)B_ * C_ * K_ / 2;   // f16 split of fch/fsh
static const size_t SZ_CW  = (size_t)L_ * C_ * C_ / 2;   // f16 split conv_w

static const size_t KNCH_OFF = 0;
static const size_t KNCL_OFF = KNCH_OFF + SZ_CKN;
static const size_t KNSH_OFF = KNCL_OFF + SZ_CKN;
static const size_t KNSL_OFF = KNSH_OFF + SZ_CKN;
static const size_t NKCH_OFF = KNSL_OFF + SZ_CKN;
static const size_t NKCL_OFF = NKCH_OFF + SZ_CNK;
static const size_t NKSH_OFF = NKCL_OFF + SZ_CNK;
static const size_t NKSL_OFF = NKSH_OFF + SZ_CNK;
static const size_t H_OFF    = NKSL_OFF + SZ_CNK;
static const size_t H2_OFF   = H_OFF + SZ_H;
static const size_t HAH_OFF  = H2_OFF + SZ_H;
static const size_t HAL_OFF  = HAH_OFF + SZ_HS;
static const size_t HTH_OFF  = HAL_OFF + SZ_HS;
static const size_t HTL_OFF  = HTH_OFF + SZ_HS;
static const size_t WQN_OFF  = HTL_OFF + SZ_HS;                  // B*N fp32
static const size_t XCH_OFF  = WQN_OFF + (size_t)B_ * N_;        // B*C*K fp32
static const size_t XSH_OFF  = XCH_OFF + (size_t)B_ * C_ * K_;
static const size_t FCHH_OFF = XSH_OFF + (size_t)B_ * C_ * K_;
static const size_t FCHL_OFF = FCHH_OFF + SZ_FS;
static const size_t FSHH_OFF = FCHL_OFF + SZ_FS;
static const size_t FSHL_OFF = FSHH_OFF + SZ_FS;
static const size_t CWH_OFF  = FSHL_OFF + SZ_FS;
static const size_t CWL_OFF  = CWH_OFF + SZ_CW;
static const size_t X0_OFF   = CWL_OFF + SZ_CW;                  // B*C
static const size_t F0_OFF   = X0_OFF + (size_t)B_ * C_;
static const size_t XCP_OFF  = F0_OFF + (size_t)B_ * C_;         // SPLIT*B*C*K
static const size_t XSP_OFF  = XCP_OFF + (size_t)SPLIT_ * B_ * C_ * K_;
// end = XSP_OFF + SPLIT*B*C*K  ~= 47.3M floats ~= 189 MB

__device__ __forceinline__ float gelu_exact(float v) {
    return v * 0.5f * (1.0f + erff(v * 0.70710678118654752440f));
}

__device__ __forceinline__ void fsplit(float v, _Float16& hi, _Float16& lo) {
    hi = (_Float16)v;
    lo = (_Float16)((v - (float)hi) * SPLIT_SCALE);
}

__device__ __forceinline__ unsigned int pack2(_Float16 a, _Float16 b) {
    union { _Float16 f[2]; unsigned int u; } x;
    x.f[0] = a; x.f[1] = b;
    return x.u;
}

__device__ __forceinline__ void unpack2(unsigned int v, _Float16& a, _Float16& b) {
    union { _Float16 f[2]; unsigned int u; } x;
    x.u = v;
    a = x.f[0]; b = x.f[1];
}

// h[b,c,n] = fc0(x);  wqn[b,n] = wq[b,ind[n]] * N
__global__ void prep_kernel(const float* __restrict__ x, const float* __restrict__ xf,
                            const int* __restrict__ ind, const float* __restrict__ fc0_w,
                            const float* __restrict__ fc0_b, float* __restrict__ h,
                            float* __restrict__ wqn) {
    int n = blockIdx.x * 256 + threadIdx.x;
    int c = blockIdx.y;
    int b = blockIdx.z;
    const float* xp = x + ((size_t)b * N_ + n) * 3;
    float acc = fc0_b[c] + xp[0] * fc0_w[0 * C_ + c] + xp[1] * fc0_w[1 * C_ + c]
              + xp[2] * fc0_w[2 * C_ + c];
    h[((size_t)b * C_ + c) * N_ + n] = acc;
    if (c == 0) {
        int g = ind[n];
        wqn[b * N_ + n] = xf[((size_t)b * NF_ + g) * 4 + 2] * (float)N_;
    }
}

// cos/sin split f16 bases in BOTH [b][k][n] and [b][n][k] layouts
__global__ __launch_bounds__(256) void bases_split(const float* __restrict__ xf,
        const int* __restrict__ ind, const float* __restrict__ modes,
        _Float16* __restrict__ knch, _Float16* __restrict__ kncl,
        _Float16* __restrict__ knsh, _Float16* __restrict__ knsl,
        _Float16* __restrict__ nkch, _Float16* __restrict__ nkcl,
        _Float16* __restrict__ nksh, _Float16* __restrict__ nksl) {
    __shared__ float lgx[64], lgy[64], lmx[64], lmy[64];
    __shared__ unsigned int lc[64][65], ls[64][65];   // [n][k] packed (hi,lo)
    int tid = threadIdx.x;
    int n0 = blockIdx.x * 64, k0 = blockIdx.y * 64, b = blockIdx.z;
    if (tid < 64) {
        int g = ind[n0 + tid];
        lgx[tid] = xf[((size_t)b * NF_ + g) * 4 + 0];
        lgy[tid] = xf[((size_t)b * NF_ + g) * 4 + 1];
    } else if (tid < 128) {
        int kk = k0 + tid - 64;
        lmx[tid - 64] = modes[kk * 2 + 0];
        lmy[tid - 64] = modes[kk * 2 + 1];
    }
    __syncthreads();
    for (int it = 0; it < 16; ++it) {
        int kl = it * 4 + (tid >> 6);
        int nl = tid & 63;
        float t = lgx[nl] * lmx[kl] + lgy[nl] * lmy[kl];
        float s, c;
        sincosf(t, &s, &c);
        _Float16 ch, cl, sh, sl;
        fsplit(c, ch, cl);
        fsplit(s, sh, sl);
        size_t o = ((size_t)b * K_ + k0 + kl) * N_ + n0 + nl;
        knch[o] = ch; kncl[o] = cl; knsh[o] = sh; knsl[o] = sl;
        lc[nl][kl] = pack2(ch, cl);
        ls[nl][kl] = pack2(sh, sl);
    }
    __syncthreads();
    for (int it = 0; it < 16; ++it) {
        int nl = it * 4 + (tid >> 6);
        int kl = tid & 63;
        _Float16 ch, cl, sh, sl;
        unpack2(lc[nl][kl], ch, cl);
        unpack2(ls[nl][kl], sh, sl);
        size_t o = ((size_t)b * N_ + n0 + nl) * K_ + k0 + kl;
        nkch[o] = ch; nkcl[o] = cl; nksh[o] = sh; nksl[o] = sl;
    }
}

// conv_w -> f16 hi/lo (all layers)
__global__ void conv_split(const float* __restrict__ conv_w, _Float16* __restrict__ cwh,
                           _Float16* __restrict__ cwl) {
    int t = blockIdx.x * 256 + threadIdx.x;
    _Float16 hi, lo;
    fsplit(conv_w[t], hi, lo);
    cwh[t] = hi; cwl[t] = lo;
}

// per-layer: hA = split(h*wqn) [c][n];  hT = split(h) [n][c]
__global__ __launch_bounds__(256) void split_h(const float* __restrict__ h,
        const float* __restrict__ wqn, _Float16* __restrict__ hah,
        _Float16* __restrict__ hal, _Float16* __restrict__ hth,
        _Float16* __restrict__ htl) {
    __shared__ unsigned int pk[64][65];
    int tid = threadIdx.x;
    int n0 = blockIdx.x * 64, c0 = blockIdx.y * 64, b = blockIdx.z;
    int col = tid & 63, row4 = tid >> 6;
    for (int r = row4; r < 64; r += 4) {
        int c = c0 + r, n = n0 + col;
        float v = h[((size_t)b * C_ + c) * N_ + n];
        _Float16 ph, pl;
        fsplit(v, ph, pl);
        pk[r][col] = pack2(ph, pl);
        float a = v * wqn[b * N_ + n];
        _Float16 ah, al;
        fsplit(a, ah, al);
        size_t o = ((size_t)b * C_ + c) * N_ + n;
        hah[o] = ah; hal[o] = al;
    }
    __syncthreads();
    for (int r = row4; r < 64; r += 4) {
        int n = n0 + r, c = c0 + col;
        _Float16 ph, pl;
        unpack2(pk[col][r], ph, pl);
        size_t o = ((size_t)b * N_ + n) * C_ + c;
        hth[o] = ph; htl[o] = pl;
    }
}

// fwd MFMA: xcp[p,b,c,k] = sum_{n in chunk p} (h*wqn)*cos ; xsp = -sum (h*wqn)*sin
// grid (K/32, SPLIT, B) = 512 blocks; block: 128c x 32k; wave: 32c x 32k (2x2 tiles)
__global__ __launch_bounds__(256) void fwd_mfma(const _Float16* __restrict__ hah,
        const _Float16* __restrict__ hal, const _Float16* __restrict__ knch,
        const _Float16* __restrict__ kncl, const _Float16* __restrict__ knsh,
        const _Float16* __restrict__ knsl, float* __restrict__ xcp,
        float* __restrict__ xsp) {
    int tid = threadIdx.x;
    int w = tid >> 6, lane = tid & 63, l15 = lane & 15, q = lane >> 4;
    int k0g = blockIdx.x * 32, p = blockIdx.y, b = blockIdx.z;
    int cstrip = w * 32;
    size_t arow[2], brow[2];
    arow[0] = ((size_t)b * C_ + cstrip + l15) * N_;
    arow[1] = arow[0] + (size_t)16 * N_;
    brow[0] = ((size_t)b * K_ + k0g + l15) * N_;
    brow[1] = brow[0] + (size_t)16 * N_;
    f32x4 z = {0.f, 0.f, 0.f, 0.f};
    f32x4 aC1[2][2], aC2[2][2], aS1[2][2], aS2[2][2];
    for (int i = 0; i < 2; ++i)
        for (int j = 0; j < 2; ++j) {
            aC1[i][j] = z; aC2[i][j] = z; aS1[i][j] = z; aS2[i][j] = z;
        }
    int nbase = p * (N_ / SPLIT_) + q * 8;
    for (int it = 0; it < (N_ / SPLIT_) / 32; ++it) {
        int off = nbase + it * 32;
        f16x8 ah[2], al[2];
        for (int mt = 0; mt < 2; ++mt) {
            ah[mt] = *(const f16x8*)(hah + arow[mt] + off);
            al[mt] = *(const f16x8*)(hal + arow[mt] + off);
        }
        f16x8 bch[2], bcl[2], bsh[2], bsl[2];
        for (int kt = 0; kt < 2; ++kt) {
            bch[kt] = *(const f16x8*)(knch + brow[kt] + off);
            bcl[kt] = *(const f16x8*)(kncl + brow[kt] + off);
            bsh[kt] = *(const f16x8*)(knsh + brow[kt] + off);
            bsl[kt] = *(const f16x8*)(knsl + brow[kt] + off);
        }
        for (int mt = 0; mt < 2; ++mt)
            for (int kt = 0; kt < 2; ++kt) {
                aC1[mt][kt] = MFMA16(ah[mt], bch[kt], aC1[mt][kt]);
                aC2[mt][kt] = MFMA16(ah[mt], bcl[kt], aC2[mt][kt]);
                aC2[mt][kt] = MFMA16(al[mt], bch[kt], aC2[mt][kt]);
                aS1[mt][kt] = MFMA16(ah[mt], bsh[kt], aS1[mt][kt]);
                aS2[mt][kt] = MFMA16(ah[mt], bsl[kt], aS2[mt][kt]);
                aS2[mt][kt] = MFMA16(al[mt], bsh[kt], aS2[mt][kt]);
            }
    }
    size_t pb = (size_t)p * B_ + b;
    for (int mt = 0; mt < 2; ++mt)
        for (int kt = 0; kt < 2; ++kt)
            for (int r = 0; r < 4; ++r) {
                int c = cstrip + mt * 16 + q * 4 + r;
                int k = k0g + kt * 16 + l15;
                size_t o = (pb * C_ + c) * K_ + k;
                xcp[o] = aC1[mt][kt][r] + aC2[mt][kt][r] * INV_SPLIT_SCALE;
                xsp[o] = -(aS1[mt][kt][r] + aS2[mt][kt][r] * INV_SPLIT_SCALE);
            }
}

__global__ void red_kernel(const float* __restrict__ xcp, const float* __restrict__ xsp,
                           float* __restrict__ xch, float* __restrict__ xsh) {
    int t = blockIdx.x * 256 + threadIdx.x;
    const int BCK = B_ * C_ * K_;
    float a = 0.f, s = 0.f;
    for (int p = 0; p < SPLIT_; ++p) {
        a += xcp[(size_t)p * BCK + t];
        s += xsp[(size_t)p * BCK + t];
    }
    xch[t] = a; xsh[t] = s;
}

// x0h[b,c] = sum_n h*wqn
__global__ void x0_kernel(const float* __restrict__ h, const float* __restrict__ wqn,
                          float* __restrict__ x0h) {
    int c = blockIdx.x, b = blockIdx.y;
    int tid = threadIdx.x;
    const float* hp = h + ((size_t)b * C_ + c) * N_;
    const float* wq = wqn + b * N_;
    float a = 0.f;
    for (int n = tid; n < N_; n += 256) a += hp[n] * wq[n];
    __shared__ float red[4];
    for (int off = 32; off; off >>= 1) a += __shfl_down(a, off, 64);
    if ((tid & 63) == 0) red[tid >> 6] = a;
    __syncthreads();
    if (tid == 0) x0h[b * C_ + c] = red[0] + red[1] + red[2] + red[3];
}

// f0h[b,o] = (sum_i x0h[b,i]*w0[l,i,o]) / NF
__global__ void f0_kernel(const float* __restrict__ x0h, const float* __restrict__ w0,
                          int l, float* __restrict__ f0h) {
    int o = threadIdx.x, b = blockIdx.x;
    const float* w = w0 + (size_t)l * C_ * C_;
    float a = 0.f;
    for (int i = 0; i < C_; ++i) a += x0h[b * C_ + i] * w[i * C_ + o];
    f0h[b * C_ + o] = a * (1.0f / NF_);
}

// fch' = (2/NF)*sum_i(xch*wc - xsh*ws); fsh' = (2/NF)*sum_i(xsh*wc + xch*ws)
// writes f16 splits directly; fsh split is NEGATED (inv only accumulates +)
__global__ __launch_bounds__(256) void mix_kernel(const float* __restrict__ xch,
        const float* __restrict__ xsh, const float* __restrict__ wc,
        const float* __restrict__ ws, int l, _Float16* __restrict__ fchh,
        _Float16* __restrict__ fchl, _Float16* __restrict__ fshh,
        _Float16* __restrict__ fshl) {
    __shared__ float red[512 * 5];
    int tid = threadIdx.x;
    int lane = tid & 63;
    int g = tid >> 6;
    int k = blockIdx.x * 64 + lane;
    int o = blockIdx.y;
    const float* wcb = wc + ((size_t)l * C_ * C_ + o) * K_ + k;
    const float* wsb = ws + ((size_t)l * C_ * C_ + o) * K_ + k;
    float fc[4] = {0, 0, 0, 0}, fs[4] = {0, 0, 0, 0};
    int i0 = g * 32;
#pragma unroll 4
    for (int ii = 0; ii < 32; ++ii) {
        int i = i0 + ii;
        float wci = wcb[(size_t)i * (C_ * K_)];
        float wsi = wsb[(size_t)i * (C_ * K_)];
#pragma unroll
        for (int b = 0; b < 4; ++b) {
            float xc = xch[((size_t)b * C_ + i) * K_ + k];
            float xs = xsh[((size_t)b * C_ + i) * K_ + k];
            fc[b] += xc * wci - xs * wsi;
            fs[b] += xs * wci + xc * wsi;
        }
    }
#pragma unroll
    for (int b = 0; b < 4; ++b) {
        red[((b * 2 + 0) * 64 + lane) * 5 + g] = fc[b];
        red[((b * 2 + 1) * 64 + lane) * 5 + g] = fs[b];
    }
    __syncthreads();
    const float sc = 2.0f / NF_;
    for (int v = tid; v < 512; v += 256) {
        float sum = (red[v * 5 + 0] + red[v * 5 + 1] + red[v * 5 + 2] + red[v * 5 + 3]) * sc;
        int lane2 = v & 63;
        int bs = v >> 6;
        int b = bs >> 1, s = bs & 1;
        size_t idx = ((size_t)b * C_ + o) * K_ + blockIdx.x * 64 + lane2;
        _Float16 hi, lo;
        if (s == 0) {
            fsplit(sum, hi, lo);
            fchh[idx] = hi; fchl[idx] = lo;
        } else {
            fsplit(-sum, hi, lo);
            fshh[idx] = hi; fshl[idx] = lo;
        }
    }
}

// inv MFMA: hnext[b,c,n] = gelu?( sum_k fch*cos + fshN*sin + sum_i cw[c,i]*h[i,n]
//                                 + f0h + conv_b )
// grid (N/32, B) = 512 blocks; block 128c x 32n; wave 32c x 32n (2x2 tiles)
__global__ __launch_bounds__(256) void inv_mfma(const _Float16* __restrict__ fchh,
        const _Float16* __restrict__ fchl, const _Float16* __restrict__ fshh,
        const _Float16* __restrict__ fshl, const _Float16* __restrict__ nkch,
        const _Float16* __restrict__ nkcl, const _Float16* __restrict__ nksh,
        const _Float16* __restrict__ nksl, const _Float16* __restrict__ cwh,
        const _Float16* __restrict__ cwl, const _Float16* __restrict__ hth,
        const _Float16* __restrict__ htl, const float* __restrict__ f0h,
        const float* __restrict__ conv_b, int l, int last, float* __restrict__ hnext) {
    int tid = threadIdx.x;
    int w = tid >> 6, lane = tid & 63, l15 = lane & 15, q = lane >> 4;
    int n0g = blockIdx.x * 32, b = blockIdx.y;
    int cstrip = w * 32;
    size_t frow[2], nrow[2], hrow[2], crow[2];
    frow[0] = ((size_t)b * C_ + cstrip + l15) * K_;
    frow[1] = frow[0] + (size_t)16 * K_;
    nrow[0] = ((size_t)b * N_ + n0g + l15) * K_;
    nrow[1] = nrow[0] + (size_t)16 * K_;
    hrow[0] = ((size_t)b * N_ + n0g + l15) * C_;
    hrow[1] = hrow[0] + (size_t)16 * C_;
    crow[0] = ((size_t)l * C_ + cstrip + l15) * C_;
    crow[1] = crow[0] + (size_t)16 * C_;
    f32x4 z = {0.f, 0.f, 0.f, 0.f};
    f32x4 a1[2][2], a2[2][2];
    for (int i = 0; i < 2; ++i)
        for (int j = 0; j < 2; ++j) { a1[i][j] = z; a2[i][j] = z; }
    // spectral: reduce over K
    for (int kc = 0; kc < K_; kc += 32) {
        int off = kc + q * 8;
        f16x8 fch_[2], fcl_[2], fsh_[2], fsl_[2];
        for (int mt = 0; mt < 2; ++mt) {
            fch_[mt] = *(const f16x8*)(fchh + frow[mt] + off);
            fcl_[mt] = *(const f16x8*)(fchl + frow[mt] + off);
            fsh_[mt] = *(const f16x8*)(fshh + frow[mt] + off);
            fsl_[mt] = *(const f16x8*)(fshl + frow[mt] + off);
        }
        f16x8 bch[2], bcl[2], bsh[2], bsl[2];
        for (int nt = 0; nt < 2; ++nt) {
            bch[nt] = *(const f16x8*)(nkch + nrow[nt] + off);
            bcl[nt] = *(const f16x8*)(nkcl + nrow[nt] + off);
            bsh[nt] = *(const f16x8*)(nksh + nrow[nt] + off);
            bsl[nt] = *(const f16x8*)(nksl + nrow[nt] + off);
        }
        for (int mt = 0; mt < 2; ++mt)
            for (int nt = 0; nt < 2; ++nt) {
                a1[mt][nt] = MFMA16(fch_[mt], bch[nt], a1[mt][nt]);
                a2[mt][nt] = MFMA16(fch_[mt], bcl[nt], a2[mt][nt]);
                a2[mt][nt] = MFMA16(fcl_[mt], bch[nt], a2[mt][nt]);
                a1[mt][nt] = MFMA16(fsh_[mt], bsh[nt], a1[mt][nt]);
                a2[mt][nt] = MFMA16(fsh_[mt], bsl[nt], a2[mt][nt]);
                a2[mt][nt] = MFMA16(fsl_[mt], bsh[nt], a2[mt][nt]);
            }
    }
    // conv: reduce over C
    for (int ic = 0; ic < C_; ic += 32) {
        int off = ic + q * 8;
        f16x8 awh[2], awl[2];
        for (int mt = 0; mt < 2; ++mt) {
            awh[mt] = *(const f16x8*)(cwh + crow[mt] + off);
            awl[mt] = *(const f16x8*)(cwl + crow[mt] + off);
        }
        f16x8 bhh[2], bhl[2];
        for (int nt = 0; nt < 2; ++nt) {
            bhh[nt] = *(const f16x8*)(hth + hrow[nt] + off);
            bhl[nt] = *(const f16x8*)(htl + hrow[nt] + off);
        }
        for (int mt = 0; mt < 2; ++mt)
            for (int nt = 0; nt < 2; ++nt) {
                a1[mt][nt] = MFMA16(awh[mt], bhh[nt], a1[mt][nt]);
                a2[mt][nt] = MFMA16(awh[mt], bhl[nt], a2[mt][nt]);
                a2[mt][nt] = MFMA16(awl[mt], bhh[nt], a2[mt][nt]);
            }
    }
    for (int mt = 0; mt < 2; ++mt)
        for (int nt = 0; nt < 2; ++nt)
            for (int r = 0; r < 4; ++r) {
                int c = cstrip + mt * 16 + q * 4 + r;
                int n = n0g + nt * 16 + l15;
                float v = a1[mt][nt][r] + a2[mt][nt][r] * INV_SPLIT_SCALE
                        + f0h[b * C_ + c] + conv_b[l * C_ + c];
                if (!last) v = gelu_exact(v);
                hnext[((size_t)b * C_ + c) * N_ + n] = v;
            }
}

// out[b,n] = fc2( gelu( fc1( h[b,:,n] ) ) )
__global__ __launch_bounds__(128) void head_kernel(const float* __restrict__ h,
        const float* __restrict__ fc1_w, const float* __restrict__ fc1_b,
        const float* __restrict__ fc2_w, const float* __restrict__ fc2_b,
        float* __restrict__ out) {
    int j = threadIdx.x;
    int bn = blockIdx.x;
    int b = bn >> 12;
    int n = bn & (N_ - 1);
    const float* hp = h + (size_t)b * C_ * N_ + n;
    float a = fc1_b[j];
    for (int c = 0; c < C_; ++c) a += hp[(size_t)c * N_] * fc1_w[c * FCD_ + j];
    a = gelu_exact(a);
    float v = a * fc2_w[j];
    for (int off = 32; off; off >>= 1) v += __shfl_down(v, off, 64);
    __shared__ float red[2];
    if ((j & 63) == 0) red[j >> 6] = v;
    __syncthreads();
    if (j == 0) out[bn] = red[0] + red[1] + fc2_b[0];
}

extern "C" void kernel_launch(void* const* d_in, const int* in_sizes, int n_in,
                              void* d_out, int out_size, void* d_ws, size_t ws_size,
                              hipStream_t stream) {
    const float* x      = (const float*)d_in[0];
    const float* xf     = (const float*)d_in[1];
    const int*   ind    = (const int*)d_in[2];
    const float* modes  = (const float*)d_in[3];
    const float* fc0_w  = (const float*)d_in[4];
    const float* fc0_b  = (const float*)d_in[5];
    const float* wc     = (const float*)d_in[6];
    const float* ws     = (const float*)d_in[7];
    const float* w0     = (const float*)d_in[8];
    const float* conv_w = (const float*)d_in[9];
    const float* conv_b = (const float*)d_in[10];
    const float* fc1_w  = (const float*)d_in[11];
    const float* fc1_b  = (const float*)d_in[12];
    const float* fc2_w  = (const float*)d_in[13];
    const float* fc2_b  = (const float*)d_in[14];
    float* out = (float*)d_out;

    float* wsf = (float*)d_ws;
    _Float16* knch = (_Float16*)(wsf + KNCH_OFF);
    _Float16* kncl = (_Float16*)(wsf + KNCL_OFF);
    _Float16* knsh = (_Float16*)(wsf + KNSH_OFF);
    _Float16* knsl = (_Float16*)(wsf + KNSL_OFF);
    _Float16* nkch = (_Float16*)(wsf + NKCH_OFF);
    _Float16* nkcl = (_Float16*)(wsf + NKCL_OFF);
    _Float16* nksh = (_Float16*)(wsf + NKSH_OFF);
    _Float16* nksl = (_Float16*)(wsf + NKSL_OFF);
    float* h   = wsf + H_OFF;
    float* h2  = wsf + H2_OFF;
    _Float16* hah = (_Float16*)(wsf + HAH_OFF);
    _Float16* hal = (_Float16*)(wsf + HAL_OFF);
    _Float16* hth = (_Float16*)(wsf + HTH_OFF);
    _Float16* htl = (_Float16*)(wsf + HTL_OFF);
    float* wqn = wsf + WQN_OFF;
    float* xch = wsf + XCH_OFF;
    float* xsh = wsf + XSH_OFF;
    _Float16* fchh = (_Float16*)(wsf + FCHH_OFF);
    _Float16* fchl = (_Float16*)(wsf + FCHL_OFF);
    _Float16* fshh = (_Float16*)(wsf + FSHH_OFF);
    _Float16* fshl = (_Float16*)(wsf + FSHL_OFF);
    _Float16* cwh = (_Float16*)(wsf + CWH_OFF);
    _Float16* cwl = (_Float16*)(wsf + CWL_OFF);
    float* x0h = wsf + X0_OFF;
    float* f0h = wsf + F0_OFF;
    float* xcp = wsf + XCP_OFF;
    float* xsp = wsf + XSP_OFF;

    prep_kernel<<<dim3(N_ / 256, C_, B_), 256, 0, stream>>>(x, xf, ind, fc0_w, fc0_b, h, wqn);
    bases_split<<<dim3(N_ / 64, K_ / 64, B_), 256, 0, stream>>>(xf, ind, modes,
        knch, kncl, knsh, knsl, nkch, nkcl, nksh, nksl);
    conv_split<<<dim3(L_ * C_ * C_ / 256), 256, 0, stream>>>(conv_w, cwh, cwl);

    float* cur = h;
    float* nxt = h2;
    for (int l = 0; l < L_; ++l) {
        split_h<<<dim3(N_ / 64, C_ / 64, B_), 256, 0, stream>>>(cur, wqn, hah, hal, hth, htl);
        fwd_mfma<<<dim3(K_ / 32, SPLIT_, B_), 256, 0, stream>>>(hah, hal, knch, kncl,
                                                                knsh, knsl, xcp, xsp);
        red_kernel<<<dim3(B_ * C_ * K_ / 256), 256, 0, stream>>>(xcp, xsp, xch, xsh);
        x0_kernel<<<dim3(C_, B_), 256, 0, stream>>>(cur, wqn, x0h);
        f0_kernel<<<dim3(B_), C_, 0, stream>>>(x0h, w0, l, f0h);
        mix_kernel<<<dim3(K_ / 64, C_), 256, 0, stream>>>(xch, xsh, wc, ws, l,
                                                          fchh, fchl, fshh, fshl);
        inv_mfma<<<dim3(N_ / 32, B_), 256, 0, stream>>>(fchh, fchl, fshh, fshl,
            nkch, nkcl, nksh, nksl, cwh, cwl, hth, htl, f0h, conv_b, l,
            (l == L_ - 1) ? 1 : 0, nxt);
        float* t = cur; cur = nxt; nxt = t;
    }
    head_kernel<<<dim3(B_ * N_), 128, 0, stream>>>(cur, fc1_w, fc1_b, fc2_w, fc2_b, out);
}

// Round 5
// 972.656 us; speedup vs baseline: 1.5861x; 1.0470x over previous
//
#include <hip/hip_runtime.h>
#include <cmath>

#define B_ 4
#define N_ 4096
#define NF_ 8192
#define K_ 512
#define C_ 128
#define L_ 4
#define FCD_ 128
#define SPLIT_ 8

typedef _Float16 f16x8 __attribute__((ext_vector_type(8)));
typedef float f32x4 __attribute__((ext_vector_type(4)));

#define MFMA16(a, b, c) __builtin_amdgcn_mfma_f32_16x16x32_f16((a), (b), (c), 0, 0, 0)

static const float SPLIT_SCALE = 2048.0f;      // 2^11
static const float INV_SPLIT_SCALE = 1.0f / 2048.0f;

// ---- workspace layout (float offsets; f16 arrays use count/2 floats) ----
static const size_t SZ_CKN = (size_t)B_ * K_ * N_ / 2;   // one f16 [b][k][n] array
static const size_t SZ_CNK = (size_t)B_ * N_ * K_ / 2;   // one f16 [b][n][k] array
static const size_t SZ_H   = (size_t)B_ * C_ * N_;       // fp32
static const size_t SZ_HS  = (size_t)B_ * C_ * N_ / 2;   // f16 split
static const size_t SZ_FS  = (size_t)B_ * C_ * K_ / 2;   // f16 split of fch/fsh
static const size_t SZ_CW  = (size_t)L_ * C_ * C_ / 2;   // f16 split conv_w
static const size_t SZ_W1  = (size_t)C_ * FCD_ / 2;      // f16 split fc1_w^T

static const size_t KNCH_OFF = 0;
static const size_t KNCL_OFF = KNCH_OFF + SZ_CKN;
static const size_t KNSH_OFF = KNCL_OFF + SZ_CKN;
static const size_t KNSL_OFF = KNSH_OFF + SZ_CKN;
static const size_t NKCH_OFF = KNSL_OFF + SZ_CKN;
static const size_t NKCL_OFF = NKCH_OFF + SZ_CNK;
static const size_t NKSH_OFF = NKCL_OFF + SZ_CNK;
static const size_t NKSL_OFF = NKSH_OFF + SZ_CNK;
static const size_t H_OFF    = NKSL_OFF + SZ_CNK;
static const size_t H2_OFF   = H_OFF + SZ_H;
static const size_t HAH_OFF  = H2_OFF + SZ_H;
static const size_t HAL_OFF  = HAH_OFF + SZ_HS;
static const size_t HTH_OFF  = HAL_OFF + SZ_HS;
static const size_t HTL_OFF  = HTH_OFF + SZ_HS;
static const size_t WQN_OFF  = HTL_OFF + SZ_HS;                  // B*N fp32
static const size_t XCH_OFF  = WQN_OFF + (size_t)B_ * N_;        // B*C*K fp32
static const size_t XSH_OFF  = XCH_OFF + (size_t)B_ * C_ * K_;
static const size_t FCHH_OFF = XSH_OFF + (size_t)B_ * C_ * K_;
static const size_t FCHL_OFF = FCHH_OFF + SZ_FS;
static const size_t FSHH_OFF = FCHL_OFF + SZ_FS;
static const size_t FSHL_OFF = FSHH_OFF + SZ_FS;
static const size_t CWH_OFF  = FSHL_OFF + SZ_FS;
static const size_t CWL_OFF  = CWH_OFF + SZ_CW;
static const size_t X0_OFF   = CWL_OFF + SZ_CW;                  // B*C
static const size_t F0_OFF   = X0_OFF + (size_t)B_ * C_;
static const size_t XCP_OFF  = F0_OFF + (size_t)B_ * C_;         // SPLIT*B*C*K
static const size_t XSP_OFF  = XCP_OFF + (size_t)SPLIT_ * B_ * C_ * K_;
static const size_t W1TH_OFF = XSP_OFF + (size_t)SPLIT_ * B_ * C_ * K_;
static const size_t W1TL_OFF = W1TH_OFF + SZ_W1;
// end ~= 47.3M floats ~= 189 MB

__device__ __forceinline__ float gelu_exact(float v) {
    return v * 0.5f * (1.0f + erff(v * 0.70710678118654752440f));
}

__device__ __forceinline__ void fsplit(float v, _Float16& hi, _Float16& lo) {
    hi = (_Float16)v;
    lo = (_Float16)((v - (float)hi) * SPLIT_SCALE);
}

__device__ __forceinline__ unsigned int pack2(_Float16 a, _Float16 b) {
    union { _Float16 f[2]; unsigned int u; } x;
    x.f[0] = a; x.f[1] = b;
    return x.u;
}

__device__ __forceinline__ void unpack2(unsigned int v, _Float16& a, _Float16& b) {
    union { _Float16 f[2]; unsigned int u; } x;
    x.u = v;
    a = x.f[0]; b = x.f[1];
}

// h[b,c,n] = fc0(x);  wqn[b,n] = wq[b,ind[n]] * N
__global__ void prep_kernel(const float* __restrict__ x, const float* __restrict__ xf,
                            const int* __restrict__ ind, const float* __restrict__ fc0_w,
                            const float* __restrict__ fc0_b, float* __restrict__ h,
                            float* __restrict__ wqn) {
    int n = blockIdx.x * 256 + threadIdx.x;
    int c = blockIdx.y;
    int b = blockIdx.z;
    const float* xp = x + ((size_t)b * N_ + n) * 3;
    float acc = fc0_b[c] + xp[0] * fc0_w[0 * C_ + c] + xp[1] * fc0_w[1 * C_ + c]
              + xp[2] * fc0_w[2 * C_ + c];
    h[((size_t)b * C_ + c) * N_ + n] = acc;
    if (c == 0) {
        int g = ind[n];
        wqn[b * N_ + n] = xf[((size_t)b * NF_ + g) * 4 + 2] * (float)N_;
    }
}

// cos/sin split f16 bases in BOTH [b][k][n] and [b][n][k] layouts
__global__ __launch_bounds__(256) void bases_split(const float* __restrict__ xf,
        const int* __restrict__ ind, const float* __restrict__ modes,
        _Float16* __restrict__ knch, _Float16* __restrict__ kncl,
        _Float16* __restrict__ knsh, _Float16* __restrict__ knsl,
        _Float16* __restrict__ nkch, _Float16* __restrict__ nkcl,
        _Float16* __restrict__ nksh, _Float16* __restrict__ nksl) {
    __shared__ float lgx[64], lgy[64], lmx[64], lmy[64];
    __shared__ unsigned int lc[64][65], ls[64][65];   // [n][k] packed (hi,lo)
    int tid = threadIdx.x;
    int n0 = blockIdx.x * 64, k0 = blockIdx.y * 64, b = blockIdx.z;
    if (tid < 64) {
        int g = ind[n0 + tid];
        lgx[tid] = xf[((size_t)b * NF_ + g) * 4 + 0];
        lgy[tid] = xf[((size_t)b * NF_ + g) * 4 + 1];
    } else if (tid < 128) {
        int kk = k0 + tid - 64;
        lmx[tid - 64] = modes[kk * 2 + 0];
        lmy[tid - 64] = modes[kk * 2 + 1];
    }
    __syncthreads();
    for (int it = 0; it < 16; ++it) {
        int kl = it * 4 + (tid >> 6);
        int nl = tid & 63;
        float t = lgx[nl] * lmx[kl] + lgy[nl] * lmy[kl];
        float s, c;
        sincosf(t, &s, &c);
        _Float16 ch, cl, sh, sl;
        fsplit(c, ch, cl);
        fsplit(s, sh, sl);
        size_t o = ((size_t)b * K_ + k0 + kl) * N_ + n0 + nl;
        knch[o] = ch; kncl[o] = cl; knsh[o] = sh; knsl[o] = sl;
        lc[nl][kl] = pack2(ch, cl);
        ls[nl][kl] = pack2(sh, sl);
    }
    __syncthreads();
    for (int it = 0; it < 16; ++it) {
        int nl = it * 4 + (tid >> 6);
        int kl = tid & 63;
        _Float16 ch, cl, sh, sl;
        unpack2(lc[nl][kl], ch, cl);
        unpack2(ls[nl][kl], sh, sl);
        size_t o = ((size_t)b * N_ + n0 + nl) * K_ + k0 + kl;
        nkch[o] = ch; nkcl[o] = cl; nksh[o] = sh; nksl[o] = sl;
    }
}

// conv_w -> f16 hi/lo (all layers)
__global__ void conv_split(const float* __restrict__ conv_w, _Float16* __restrict__ cwh,
                           _Float16* __restrict__ cwl) {
    int t = blockIdx.x * 256 + threadIdx.x;
    _Float16 hi, lo;
    fsplit(conv_w[t], hi, lo);
    cwh[t] = hi; cwl[t] = lo;
}

// fc1_w^T -> f16 hi/lo  (w1t[j][c] = fc1_w[c][j])
__global__ void w1_split(const float* __restrict__ fc1_w, _Float16* __restrict__ w1th,
                         _Float16* __restrict__ w1tl) {
    int t = blockIdx.x * 256 + threadIdx.x;   // t = j*C_ + c
    int j = t >> 7, c = t & (C_ - 1);
    _Float16 hi, lo;
    fsplit(fc1_w[c * FCD_ + j], hi, lo);
    w1th[t] = hi; w1tl[t] = lo;
}

// per-layer: hA = split(h*wqn) [c][n];  hT = split(h) [n][c]
__global__ __launch_bounds__(256) void split_h(const float* __restrict__ h,
        const float* __restrict__ wqn, _Float16* __restrict__ hah,
        _Float16* __restrict__ hal, _Float16* __restrict__ hth,
        _Float16* __restrict__ htl) {
    __shared__ unsigned int pk[64][65];
    int tid = threadIdx.x;
    int n0 = blockIdx.x * 64, c0 = blockIdx.y * 64, b = blockIdx.z;
    int col = tid & 63, row4 = tid >> 6;
    for (int r = row4; r < 64; r += 4) {
        int c = c0 + r, n = n0 + col;
        float v = h[((size_t)b * C_ + c) * N_ + n];
        _Float16 ph, pl;
        fsplit(v, ph, pl);
        pk[r][col] = pack2(ph, pl);
        float a = v * wqn[b * N_ + n];
        _Float16 ah, al;
        fsplit(a, ah, al);
        size_t o = ((size_t)b * C_ + c) * N_ + n;
        hah[o] = ah; hal[o] = al;
    }
    __syncthreads();
    for (int r = row4; r < 64; r += 4) {
        int n = n0 + r, c = c0 + col;
        _Float16 ph, pl;
        unpack2(pk[col][r], ph, pl);
        size_t o = ((size_t)b * N_ + n) * C_ + c;
        hth[o] = ph; htl[o] = pl;
    }
}

// fwd MFMA: xcp[p,b,c,k] = sum_{n in chunk p} (h*wqn)*cos ; xsp = -sum (h*wqn)*sin
// grid (K/32, SPLIT, B) = 512 blocks; block: 128c x 32k; wave: 32c x 32k (2x2 tiles)
__global__ __launch_bounds__(256) void fwd_mfma(const _Float16* __restrict__ hah,
        const _Float16* __restrict__ hal, const _Float16* __restrict__ knch,
        const _Float16* __restrict__ kncl, const _Float16* __restrict__ knsh,
        const _Float16* __restrict__ knsl, float* __restrict__ xcp,
        float* __restrict__ xsp) {
    int tid = threadIdx.x;
    int w = tid >> 6, lane = tid & 63, l15 = lane & 15, q = lane >> 4;
    int k0g = blockIdx.x * 32, p = blockIdx.y, b = blockIdx.z;
    int cstrip = w * 32;
    size_t arow[2], brow[2];
    arow[0] = ((size_t)b * C_ + cstrip + l15) * N_;
    arow[1] = arow[0] + (size_t)16 * N_;
    brow[0] = ((size_t)b * K_ + k0g + l15) * N_;
    brow[1] = brow[0] + (size_t)16 * N_;
    f32x4 z = {0.f, 0.f, 0.f, 0.f};
    f32x4 aC1[2][2], aC2[2][2], aS1[2][2], aS2[2][2];
    for (int i = 0; i < 2; ++i)
        for (int j = 0; j < 2; ++j) {
            aC1[i][j] = z; aC2[i][j] = z; aS1[i][j] = z; aS2[i][j] = z;
        }
    int nbase = p * (N_ / SPLIT_) + q * 8;
    for (int it = 0; it < (N_ / SPLIT_) / 32; ++it) {
        int off = nbase + it * 32;
        f16x8 ah[2], al[2];
        for (int mt = 0; mt < 2; ++mt) {
            ah[mt] = *(const f16x8*)(hah + arow[mt] + off);
            al[mt] = *(const f16x8*)(hal + arow[mt] + off);
        }
        f16x8 bch[2], bcl[2], bsh[2], bsl[2];
        for (int kt = 0; kt < 2; ++kt) {
            bch[kt] = *(const f16x8*)(knch + brow[kt] + off);
            bcl[kt] = *(const f16x8*)(kncl + brow[kt] + off);
            bsh[kt] = *(const f16x8*)(knsh + brow[kt] + off);
            bsl[kt] = *(const f16x8*)(knsl + brow[kt] + off);
        }
        for (int mt = 0; mt < 2; ++mt)
            for (int kt = 0; kt < 2; ++kt) {
                aC1[mt][kt] = MFMA16(ah[mt], bch[kt], aC1[mt][kt]);
                aC2[mt][kt] = MFMA16(ah[mt], bcl[kt], aC2[mt][kt]);
                aC2[mt][kt] = MFMA16(al[mt], bch[kt], aC2[mt][kt]);
                aS1[mt][kt] = MFMA16(ah[mt], bsh[kt], aS1[mt][kt]);
                aS2[mt][kt] = MFMA16(ah[mt], bsl[kt], aS2[mt][kt]);
                aS2[mt][kt] = MFMA16(al[mt], bsh[kt], aS2[mt][kt]);
            }
    }
    size_t pb = (size_t)p * B_ + b;
    for (int mt = 0; mt < 2; ++mt)
        for (int kt = 0; kt < 2; ++kt)
            for (int r = 0; r < 4; ++r) {
                int c = cstrip + mt * 16 + q * 4 + r;
                int k = k0g + kt * 16 + l15;
                size_t o = (pb * C_ + c) * K_ + k;
                xcp[o] = aC1[mt][kt][r] + aC2[mt][kt][r] * INV_SPLIT_SCALE;
                xsp[o] = -(aS1[mt][kt][r] + aS2[mt][kt][r] * INV_SPLIT_SCALE);
            }
}

__global__ void red_kernel(const float* __restrict__ xcp, const float* __restrict__ xsp,
                           float* __restrict__ xch, float* __restrict__ xsh) {
    int t = blockIdx.x * 256 + threadIdx.x;
    const int BCK = B_ * C_ * K_;
    float a = 0.f, s = 0.f;
    for (int p = 0; p < SPLIT_; ++p) {
        a += xcp[(size_t)p * BCK + t];
        s += xsp[(size_t)p * BCK + t];
    }
    xch[t] = a; xsh[t] = s;
}

// x0h[b,c] = sum_n h*wqn
__global__ void x0_kernel(const float* __restrict__ h, const float* __restrict__ wqn,
                          float* __restrict__ x0h) {
    int c = blockIdx.x, b = blockIdx.y;
    int tid = threadIdx.x;
    const float* hp = h + ((size_t)b * C_ + c) * N_;
    const float* wq = wqn + b * N_;
    float a = 0.f;
    for (int n = tid; n < N_; n += 256) a += hp[n] * wq[n];
    __shared__ float red[4];
    for (int off = 32; off; off >>= 1) a += __shfl_down(a, off, 64);
    if ((tid & 63) == 0) red[tid >> 6] = a;
    __syncthreads();
    if (tid == 0) x0h[b * C_ + c] = red[0] + red[1] + red[2] + red[3];
}

// f0h[b,o] = (sum_i x0h[b,i]*w0[l,i,o]) / NF
__global__ void f0_kernel(const float* __restrict__ x0h, const float* __restrict__ w0,
                          int l, float* __restrict__ f0h) {
    int o = threadIdx.x, b = blockIdx.x;
    const float* w = w0 + (size_t)l * C_ * C_;
    float a = 0.f;
    for (int i = 0; i < C_; ++i) a += x0h[b * C_ + i] * w[i * C_ + o];
    f0h[b * C_ + o] = a * (1.0f / NF_);
}

// fch' = (2/NF)*sum_i(xch*wc - xsh*ws); fsh' = (2/NF)*sum_i(xsh*wc + xch*ws)
// writes f16 splits directly; fsh split is NEGATED (inv only accumulates +)
__global__ __launch_bounds__(256) void mix_kernel(const float* __restrict__ xch,
        const float* __restrict__ xsh, const float* __restrict__ wc,
        const float* __restrict__ ws, int l, _Float16* __restrict__ fchh,
        _Float16* __restrict__ fchl, _Float16* __restrict__ fshh,
        _Float16* __restrict__ fshl) {
    __shared__ float red[512 * 5];
    int tid = threadIdx.x;
    int lane = tid & 63;
    int g = tid >> 6;
    int k = blockIdx.x * 64 + lane;
    int o = blockIdx.y;
    const float* wcb = wc + ((size_t)l * C_ * C_ + o) * K_ + k;
    const float* wsb = ws + ((size_t)l * C_ * C_ + o) * K_ + k;
    float fc[4] = {0, 0, 0, 0}, fs[4] = {0, 0, 0, 0};
    int i0 = g * 32;
#pragma unroll 4
    for (int ii = 0; ii < 32; ++ii) {
        int i = i0 + ii;
        float wci = wcb[(size_t)i * (C_ * K_)];
        float wsi = wsb[(size_t)i * (C_ * K_)];
#pragma unroll
        for (int b = 0; b < 4; ++b) {
            float xc = xch[((size_t)b * C_ + i) * K_ + k];
            float xs = xsh[((size_t)b * C_ + i) * K_ + k];
            fc[b] += xc * wci - xs * wsi;
            fs[b] += xs * wci + xc * wsi;
        }
    }
#pragma unroll
    for (int b = 0; b < 4; ++b) {
        red[((b * 2 + 0) * 64 + lane) * 5 + g] = fc[b];
        red[((b * 2 + 1) * 64 + lane) * 5 + g] = fs[b];
    }
    __syncthreads();
    const float sc = 2.0f / NF_;
    for (int v = tid; v < 512; v += 256) {
        float sum = (red[v * 5 + 0] + red[v * 5 + 1] + red[v * 5 + 2] + red[v * 5 + 3]) * sc;
        int lane2 = v & 63;
        int bs = v >> 6;
        int b = bs >> 1, s = bs & 1;
        size_t idx = ((size_t)b * C_ + o) * K_ + blockIdx.x * 64 + lane2;
        _Float16 hi, lo;
        if (s == 0) {
            fsplit(sum, hi, lo);
            fchh[idx] = hi; fchl[idx] = lo;
        } else {
            fsplit(-sum, hi, lo);
            fshh[idx] = hi; fshl[idx] = lo;
        }
    }
}

// inv MFMA: hnext[b,c,n] = gelu?( sum_k fch*cos + fshN*sin + sum_i cw[c,i]*h[i,n]
//                                 + f0h + conv_b )
// grid (N/32, B) = 512 blocks; block 128c x 32n; wave 32c x 32n (2x2 tiles)
__global__ __launch_bounds__(256) void inv_mfma(const _Float16* __restrict__ fchh,
        const _Float16* __restrict__ fchl, const _Float16* __restrict__ fshh,
        const _Float16* __restrict__ fshl, const _Float16* __restrict__ nkch,
        const _Float16* __restrict__ nkcl, const _Float16* __restrict__ nksh,
        const _Float16* __restrict__ nksl, const _Float16* __restrict__ cwh,
        const _Float16* __restrict__ cwl, const _Float16* __restrict__ hth,
        const _Float16* __restrict__ htl, const float* __restrict__ f0h,
        const float* __restrict__ conv_b, int l, int last, float* __restrict__ hnext) {
    int tid = threadIdx.x;
    int w = tid >> 6, lane = tid & 63, l15 = lane & 15, q = lane >> 4;
    int n0g = blockIdx.x * 32, b = blockIdx.y;
    int cstrip = w * 32;
    size_t frow[2], nrow[2], hrow[2], crow[2];
    frow[0] = ((size_t)b * C_ + cstrip + l15) * K_;
    frow[1] = frow[0] + (size_t)16 * K_;
    nrow[0] = ((size_t)b * N_ + n0g + l15) * K_;
    nrow[1] = nrow[0] + (size_t)16 * K_;
    hrow[0] = ((size_t)b * N_ + n0g + l15) * C_;
    hrow[1] = hrow[0] + (size_t)16 * C_;
    crow[0] = ((size_t)l * C_ + cstrip + l15) * C_;
    crow[1] = crow[0] + (size_t)16 * C_;
    f32x4 z = {0.f, 0.f, 0.f, 0.f};
    f32x4 a1[2][2], a2[2][2];
    for (int i = 0; i < 2; ++i)
        for (int j = 0; j < 2; ++j) { a1[i][j] = z; a2[i][j] = z; }
    // spectral: reduce over K
    for (int kc = 0; kc < K_; kc += 32) {
        int off = kc + q * 8;
        f16x8 fch_[2], fcl_[2], fsh_[2], fsl_[2];
        for (int mt = 0; mt < 2; ++mt) {
            fch_[mt] = *(const f16x8*)(fchh + frow[mt] + off);
            fcl_[mt] = *(const f16x8*)(fchl + frow[mt] + off);
            fsh_[mt] = *(const f16x8*)(fshh + frow[mt] + off);
            fsl_[mt] = *(const f16x8*)(fshl + frow[mt] + off);
        }
        f16x8 bch[2], bcl[2], bsh[2], bsl[2];
        for (int nt = 0; nt < 2; ++nt) {
            bch[nt] = *(const f16x8*)(nkch + nrow[nt] + off);
            bcl[nt] = *(const f16x8*)(nkcl + nrow[nt] + off);
            bsh[nt] = *(const f16x8*)(nksh + nrow[nt] + off);
            bsl[nt] = *(const f16x8*)(nksl + nrow[nt] + off);
        }
        for (int mt = 0; mt < 2; ++mt)
            for (int nt = 0; nt < 2; ++nt) {
                a1[mt][nt] = MFMA16(fch_[mt], bch[nt], a1[mt][nt]);
                a2[mt][nt] = MFMA16(fch_[mt], bcl[nt], a2[mt][nt]);
                a2[mt][nt] = MFMA16(fcl_[mt], bch[nt], a2[mt][nt]);
                a1[mt][nt] = MFMA16(fsh_[mt], bsh[nt], a1[mt][nt]);
                a2[mt][nt] = MFMA16(fsh_[mt], bsl[nt], a2[mt][nt]);
                a2[mt][nt] = MFMA16(fsl_[mt], bsh[nt], a2[mt][nt]);
            }
    }
    // conv: reduce over C
    for (int ic = 0; ic < C_; ic += 32) {
        int off = ic + q * 8;
        f16x8 awh[2], awl[2];
        for (int mt = 0; mt < 2; ++mt) {
            awh[mt] = *(const f16x8*)(cwh + crow[mt] + off);
            awl[mt] = *(const f16x8*)(cwl + crow[mt] + off);
        }
        f16x8 bhh[2], bhl[2];
        for (int nt = 0; nt < 2; ++nt) {
            bhh[nt] = *(const f16x8*)(hth + hrow[nt] + off);
            bhl[nt] = *(const f16x8*)(htl + hrow[nt] + off);
        }
        for (int mt = 0; mt < 2; ++mt)
            for (int nt = 0; nt < 2; ++nt) {
                a1[mt][nt] = MFMA16(awh[mt], bhh[nt], a1[mt][nt]);
                a2[mt][nt] = MFMA16(awh[mt], bhl[nt], a2[mt][nt]);
                a2[mt][nt] = MFMA16(awl[mt], bhh[nt], a2[mt][nt]);
            }
    }
    for (int mt = 0; mt < 2; ++mt)
        for (int nt = 0; nt < 2; ++nt)
            for (int r = 0; r < 4; ++r) {
                int c = cstrip + mt * 16 + q * 4 + r;
                int n = n0g + nt * 16 + l15;
                float v = a1[mt][nt][r] + a2[mt][nt][r] * INV_SPLIT_SCALE
                        + f0h[b * C_ + c] + conv_b[l * C_ + c];
                if (!last) v = gelu_exact(v);
                hnext[((size_t)b * C_ + c) * N_ + n] = v;
            }
}

// head via MFMA: out[b,n] = fc2_b + sum_j fc2_w[j]*gelu(fc1_b[j] + sum_c w1t[j,c]*h[c,n])
// grid (N/32, B) = 512 blocks; block 128j x 32n; wave 32j x 32n (2x2 tiles)
__global__ __launch_bounds__(256) void head_mfma(const _Float16* __restrict__ hth,
        const _Float16* __restrict__ htl, const _Float16* __restrict__ w1th,
        const _Float16* __restrict__ w1tl, const float* __restrict__ fc1_b,
        const float* __restrict__ fc2_w, const float* __restrict__ fc2_b,
        float* __restrict__ out) {
    __shared__ float red[4][4][2][16];   // [wave][quad][nt][l15]
    int tid = threadIdx.x;
    int w = tid >> 6, lane = tid & 63, l15 = lane & 15, q = lane >> 4;
    int n0 = blockIdx.x * 32, b = blockIdx.y;
    int jstrip = w * 32;
    size_t wrow[2], hrow[2];
    wrow[0] = (size_t)(jstrip + l15) * C_;
    wrow[1] = wrow[0] + (size_t)16 * C_;
    hrow[0] = ((size_t)b * N_ + n0 + l15) * C_;
    hrow[1] = hrow[0] + (size_t)16 * C_;
    f32x4 z = {0.f, 0.f, 0.f, 0.f};
    f32x4 a1[2][2], a2[2][2];
    for (int i = 0; i < 2; ++i)
        for (int j = 0; j < 2; ++j) { a1[i][j] = z; a2[i][j] = z; }
    for (int cc = 0; cc < C_; cc += 32) {
        int off = cc + q * 8;
        f16x8 ah[2], al[2], bh[2], bl[2];
        for (int mt = 0; mt < 2; ++mt) {
            ah[mt] = *(const f16x8*)(w1th + wrow[mt] + off);
            al[mt] = *(const f16x8*)(w1tl + wrow[mt] + off);
        }
        for (int nt = 0; nt < 2; ++nt) {
            bh[nt] = *(const f16x8*)(hth + hrow[nt] + off);
            bl[nt] = *(const f16x8*)(htl + hrow[nt] + off);
        }
        for (int mt = 0; mt < 2; ++mt)
            for (int nt = 0; nt < 2; ++nt) {
                a1[mt][nt] = MFMA16(ah[mt], bh[nt], a1[mt][nt]);
                a2[mt][nt] = MFMA16(ah[mt], bl[nt], a2[mt][nt]);
                a2[mt][nt] = MFMA16(al[mt], bh[nt], a2[mt][nt]);
            }
    }
    float p[2] = {0.f, 0.f};
    for (int mt = 0; mt < 2; ++mt)
        for (int nt = 0; nt < 2; ++nt)
            for (int r = 0; r < 4; ++r) {
                int j = jstrip + mt * 16 + q * 4 + r;
                float v = a1[mt][nt][r] + a2[mt][nt][r] * INV_SPLIT_SCALE + fc1_b[j];
                p[nt] += gelu_exact(v) * fc2_w[j];
            }
    red[w][q][0][l15] = p[0];
    red[w][q][1][l15] = p[1];
    __syncthreads();
    if (tid < 32) {
        int nt = tid >> 4, nl = tid & 15;
        float s = 0.f;
        for (int ww = 0; ww < 4; ++ww)
            for (int qq = 0; qq < 4; ++qq) s += red[ww][qq][nt][nl];
        out[(size_t)b * N_ + n0 + nt * 16 + nl] = s + fc2_b[0];
    }
}

extern "C" void kernel_launch(void* const* d_in, const int* in_sizes, int n_in,
                              void* d_out, int out_size, void* d_ws, size_t ws_size,
                              hipStream_t stream) {
    const float* x      = (const float*)d_in[0];
    const float* xf     = (const float*)d_in[1];
    const int*   ind    = (const int*)d_in[2];
    const float* modes  = (const float*)d_in[3];
    const float* fc0_w  = (const float*)d_in[4];
    const float* fc0_b  = (const float*)d_in[5];
    const float* wc     = (const float*)d_in[6];
    const float* ws     = (const float*)d_in[7];
    const float* w0     = (const float*)d_in[8];
    const float* conv_w = (const float*)d_in[9];
    const float* conv_b = (const float*)d_in[10];
    const float* fc1_w  = (const float*)d_in[11];
    const float* fc1_b  = (const float*)d_in[12];
    const float* fc2_w  = (const float*)d_in[13];
    const float* fc2_b  = (const float*)d_in[14];
    float* out = (float*)d_out;

    float* wsf = (float*)d_ws;
    _Float16* knch = (_Float16*)(wsf + KNCH_OFF);
    _Float16* kncl = (_Float16*)(wsf + KNCL_OFF);
    _Float16* knsh = (_Float16*)(wsf + KNSH_OFF);
    _Float16* knsl = (_Float16*)(wsf + KNSL_OFF);
    _Float16* nkch = (_Float16*)(wsf + NKCH_OFF);
    _Float16* nkcl = (_Float16*)(wsf + NKCL_OFF);
    _Float16* nksh = (_Float16*)(wsf + NKSH_OFF);
    _Float16* nksl = (_Float16*)(wsf + NKSL_OFF);
    float* h   = wsf + H_OFF;
    float* h2  = wsf + H2_OFF;
    _Float16* hah = (_Float16*)(wsf + HAH_OFF);
    _Float16* hal = (_Float16*)(wsf + HAL_OFF);
    _Float16* hth = (_Float16*)(wsf + HTH_OFF);
    _Float16* htl = (_Float16*)(wsf + HTL_OFF);
    float* wqn = wsf + WQN_OFF;
    float* xch = wsf + XCH_OFF;
    float* xsh = wsf + XSH_OFF;
    _Float16* fchh = (_Float16*)(wsf + FCHH_OFF);
    _Float16* fchl = (_Float16*)(wsf + FCHL_OFF);
    _Float16* fshh = (_Float16*)(wsf + FSHH_OFF);
    _Float16* fshl = (_Float16*)(wsf + FSHL_OFF);
    _Float16* cwh = (_Float16*)(wsf + CWH_OFF);
    _Float16* cwl = (_Float16*)(wsf + CWL_OFF);
    float* x0h = wsf + X0_OFF;
    float* f0h = wsf + F0_OFF;
    float* xcp = wsf + XCP_OFF;
    float* xsp = wsf + XSP_OFF;
    _Float16* w1th = (_Float16*)(wsf + W1TH_OFF);
    _Float16* w1tl = (_Float16*)(wsf + W1TL_OFF);

    prep_kernel<<<dim3(N_ / 256, C_, B_), 256, 0, stream>>>(x, xf, ind, fc0_w, fc0_b, h, wqn);
    bases_split<<<dim3(N_ / 64, K_ / 64, B_), 256, 0, stream>>>(xf, ind, modes,
        knch, kncl, knsh, knsl, nkch, nkcl, nksh, nksl);
    conv_split<<<dim3(L_ * C_ * C_ / 256), 256, 0, stream>>>(conv_w, cwh, cwl);
    w1_split<<<dim3(C_ * FCD_ / 256), 256, 0, stream>>>(fc1_w, w1th, w1tl);

    float* cur = h;
    float* nxt = h2;
    for (int l = 0; l < L_; ++l) {
        split_h<<<dim3(N_ / 64, C_ / 64, B_), 256, 0, stream>>>(cur, wqn, hah, hal, hth, htl);
        fwd_mfma<<<dim3(K_ / 32, SPLIT_, B_), 256, 0, stream>>>(hah, hal, knch, kncl,
                                                                knsh, knsl, xcp, xsp);
        red_kernel<<<dim3(B_ * C_ * K_ / 256), 256, 0, stream>>>(xcp, xsp, xch, xsh);
        x0_kernel<<<dim3(C_, B_), 256, 0, stream>>>(cur, wqn, x0h);
        f0_kernel<<<dim3(B_), C_, 0, stream>>>(x0h, w0, l, f0h);
        mix_kernel<<<dim3(K_ / 64, C_), 256, 0, stream>>>(xch, xsh, wc, ws, l,
                                                          fchh, fchl, fshh, fshl);
        inv_mfma<<<dim3(N_ / 32, B_), 256, 0, stream>>>(fchh, fchl, fshh, fshl,
            nkch, nkcl, nksh, nksl, cwh, cwl, hth, htl, f0h, conv_b, l,
            (l == L_ - 1) ? 1 : 0, nxt);
        float* t = cur; cur = nxt; nxt = t;
    }
    split_h<<<dim3(N_ / 64, C_ / 64, B_), 256, 0, stream>>>(cur, wqn, hah, hal, hth, htl);
    head_mfma<<<dim3(N_ / 32, B_), 256, 0, stream>>>(hth, htl, w1th, w1tl,
                                                     fc1_b, fc2_w, fc2_b, out);
}